// Round 4
// baseline (1531.656 us; speedup 1.0000x reference)
//
#include <hip/hip_runtime.h>
#include <math.h>

#define NLOR   65536
#define NLORP  67584              /* 65536 + 2048 pad slots, multiple of 1024 */
#define NG     128
#define PLANE  (NG * NG)
#define NSUB   4

#define VOX    1.671875f          /* 214/128 exact */
#define XMIN  (-107.0f)
#define INV2S2 ((float)(3.14159265358979323846 / (2.0 * (214.0/128.0) * (214.0/128.0))))

// ---------------------------------------------------------------------------
// LOR reorder: counting sort by (slope class, j at mid-plane), 64-way
// transposed interleave within each slope class so each wave's lanes have
// evenly-spread j (bank-disjoint LDS atomics) with nearly-equal slope.
// ---------------------------------------------------------------------------
__device__ __forceinline__ int sort_key(const float* __restrict__ lors, int lor)
{
    const float p1y = lors[1 * NLOR + lor];
    const float p1z = lors[2 * NLOR + lor];
    const float dy  = lors[4 * NLOR + lor] - p1y;
    float dz = lors[5 * NLOR + lor] - p1z;
    dz = (fabsf(dz) < 1e-6f) ? 1e-6f : dz;
    const float slope = dy / dz;
    int s = (int)floorf((slope + 1.0f) * 16.0f);
    s = min(max(s, 0), 31);
    const float zc = XMIN + 64.5f * VOX;
    const float t  = (zc - p1z) / dz;
    const float ys = p1y + t * dy;
    int j = (int)rintf((ys - XMIN) / VOX - 0.5f);
    j = min(max(j, 0), 127);
    return s * 128 + j;
}

__global__ __launch_bounds__(1024)
void sort_hist(const float* __restrict__ lors, int* __restrict__ hist)
{
    __shared__ int h[4096];
    const int tid = threadIdx.x;
    for (int i = tid; i < 4096; i += 1024) h[i] = 0;
    __syncthreads();
    const int lor = blockIdx.x * 1024 + tid;
    atomicAdd(&h[sort_key(lors, lor)], 1);
    __syncthreads();
    for (int i = tid; i < 4096; i += 1024) if (h[i]) atomicAdd(&hist[i], h[i]);
}

__global__ __launch_bounds__(1024)
void sort_scan(const int* __restrict__ hist, int* __restrict__ off,
               int* __restrict__ base, int* __restrict__ rows, int* __restrict__ padbase)
{
    __shared__ int ts[1024];
    const int tid = threadIdx.x;
    const int a0 = hist[4 * tid], a1 = hist[4 * tid + 1];
    const int a2 = hist[4 * tid + 2], a3 = hist[4 * tid + 3];
    ts[tid] = a0 + a1 + a2 + a3;
    __syncthreads();
    for (int d = 1; d < 1024; d <<= 1) {
        const int v = (tid >= d) ? ts[tid - d] : 0;
        __syncthreads();
        ts[tid] += v;
        __syncthreads();
    }
    const int excl = tid ? ts[tid - 1] : 0;
    off[4 * tid]     = excl;
    off[4 * tid + 1] = excl + a0;
    off[4 * tid + 2] = excl + a0 + a1;
    off[4 * tid + 3] = excl + a0 + a1 + a2;
    __syncthreads();
    if (tid == 0) {
        for (int s = 0; s < 32; ++s) base[s] = off[s << 7];
        base[32] = NLOR;
        int pb = 0;
        for (int s = 0; s < 32; ++s) {
            const int M = base[s + 1] - base[s];
            const int r = (M + 63) >> 6;
            rows[s] = r; padbase[s] = pb; pb += r << 6;
        }
    }
}

__global__ __launch_bounds__(1024)
void sort_scatter(const float* __restrict__ lors, float* __restrict__ lorsR,
                  const int* __restrict__ off, int* __restrict__ cnt,
                  const int* __restrict__ base, const int* __restrict__ rows,
                  const int* __restrict__ padbase)
{
    const int lor = blockIdx.x * 1024 + threadIdx.x;
    const int key = sort_key(lors, lor);
    const int r   = atomicAdd(&cnt[key], 1);
    const int R   = off[key] + r;
    const int s   = key >> 7;
    const int rs  = R - base[s];
    const int rw  = rows[s];
    const int p   = padbase[s] + (rs % rw) * 64 + rs / rw;
#pragma unroll
    for (int c = 0; c < 6; ++c) lorsR[c * NLORP + p] = lors[c * NLOR + lor];
}

// ---------------------------------------------------------------------------
__device__ __forceinline__ void lor_geom(const float* __restrict__ lors, int lor,
    float& p1x, float& p1y, float& p1z,
    float& dx, float& dy, float& dz, float& dl)
{
    p1x = lors[0 * NLORP + lor];
    p1y = lors[1 * NLORP + lor];
    p1z = lors[2 * NLORP + lor];
    const float p2x = lors[3 * NLORP + lor];
    const float p2y = lors[4 * NLORP + lor];
    const float p2z = lors[5 * NLORP + lor];
    dx = p2x - p1x; dy = p2y - p1y;
    const float dz0 = p2z - p1z;
    const float L = sqrtf(dx * dx + dy * dy + dz0 * dz0);
    dz = (fabsf(dz0) < 1e-6f) ? 1e-6f : dz0;
    dl = VOX * L / fabsf(dz);
}

__device__ __forceinline__ void axis_w(int c0, float xs, float* e, int* c)
{
#pragma unroll
    for (int o = 0; o < 3; ++o) {
        const int i = c0 + o - 1;
        const int ic = min(max(i, 0), NG - 1);
        const float d = XMIN + ((float)ic + 0.5f) * VOX - xs;
        float w = __expf(-d * d * INV2S2);
        e[o] = (i >= 0 && i < NG) ? w : 0.0f;
        c[o] = ic;
    }
}

// ---------------------------------------------------------------------------
template<int SP, int SQ, int SR, int CONTIG, int NSUM, bool ACCUM>
__global__ __launch_bounds__(256)
void permute_k(const float* __restrict__ in, float* __restrict__ out)
{
    __shared__ float tile[32][33];
    const int b  = blockIdx.z;
    const int c0 = blockIdx.x * 32;
    const int r0 = blockIdx.y * 32;
    const int tx = threadIdx.x, ty = threadIdx.y;

#pragma unroll
    for (int m = 0; m < 4; ++m) {
        const int C = c0 + tx;
        const int R = r0 + ty + 8 * m;
        const int P = (CONTIG == 0) ? C : b;
        const int Q = (CONTIG == 0) ? b : C;
        const int a = P * SP + Q * SQ + R * SR;
        float v = 0.0f;
#pragma unroll
        for (int s = 0; s < NSUM; ++s) v += in[a + s * NG * PLANE];
        tile[ty + 8 * m][tx] = v;
    }
    __syncthreads();
#pragma unroll
    for (int m = 0; m < 4; ++m) {
        const int R = r0 + tx;
        const int C = c0 + ty + 8 * m;
        const int P = (CONTIG == 0) ? C : b;
        const int Q = (CONTIG == 0) ? b : C;
        const int o = P * PLANE + Q * NG + R;
        if (ACCUM) out[o] += tile[tx][ty + 8 * m];
        else       out[o]  = tile[tx][ty + 8 * m];
    }
}

// ---------------------------------------------------------------------------
__global__ __launch_bounds__(1024)
void plane_proj(const float* __restrict__ lors, const float* __restrict__ imgP,
                float* __restrict__ part)
{
    __shared__ float pl[PLANE];
    const int k    = blockIdx.x >> 1;
    const int half = blockIdx.x & 1;
    const int tid  = threadIdx.x;

    const float4* src = (const float4*)(imgP + k * PLANE);
    float4* dst = (float4*)pl;
    for (int i = tid; i < PLANE / 4; i += 1024) dst[i] = src[i];
    __syncthreads();

    const float zc = XMIN + ((float)k + 0.5f) * VOX;
    const int lo = half * (NLORP / 2), hi = lo + NLORP / 2;
    for (int lor = lo + tid; lor < hi; lor += 1024) {
        float p1x, p1y, p1z, dx, dy, dz, dl;
        lor_geom(lors, lor, p1x, p1y, p1z, dx, dy, dz, dl);
        const float t  = (zc - p1z) / dz;
        const float xs = p1x + t * dx;
        const float ys = p1y + t * dy;
        const int i0 = (int)rintf((xs - XMIN) / VOX - 0.5f);
        const int j0 = (int)rintf((ys - XMIN) / VOX - 0.5f);
        const bool tin = (t >= 0.0f) && (t <= 1.0f);
        float ex[3], ey[3]; int ci[3], cj[3];
        axis_w(i0, xs, ex, ci);
        axis_w(j0, ys, ey, cj);
        float s = 0.0f;
        if (tin) {
#pragma unroll
            for (int a = 0; a < 3; ++a) {
                float r = 0.0f;
#pragma unroll
                for (int bo = 0; bo < 3; ++bo) r += ey[bo] * pl[ci[a] * NG + cj[bo]];
                s += ex[a] * r;
            }
        }
        part[k * NLORP + lor] = s;
    }
}

__global__ __launch_bounds__(256)
void reduce_cf(const float* __restrict__ lors, const float* __restrict__ part,
               float* __restrict__ cf)
{
    const int lor = blockIdx.x * 256 + threadIdx.x;
    float s = 0.0f;
    for (int k = 0; k < NG; ++k) s += part[k * NLORP + lor];
    float p1x, p1y, p1z, dx, dy, dz, dl;
    lor_geom(lors, lor, p1x, p1y, p1z, dx, dy, dz, dl);
    const float proj = s * dl;
    cf[lor] = dl / (proj + 1e-8f);
}

__global__ __launch_bounds__(1024)
void plane_bp(const float* __restrict__ lors, const float* __restrict__ cf,
              float* __restrict__ bpsub)
{
    __shared__ float pl[PLANE];
    const int k   = blockIdx.x >> 2;
    const int sub = blockIdx.x & 3;
    const int tid = threadIdx.x;

    const float4 z4 = {0.0f, 0.0f, 0.0f, 0.0f};
    float4* dst = (float4*)pl;
    for (int i = tid; i < PLANE / 4; i += 1024) dst[i] = z4;
    __syncthreads();

    const float zc = XMIN + ((float)k + 0.5f) * VOX;
    const int lo = sub * (NLORP / NSUB), hi = lo + NLORP / NSUB;
    for (int lor = lo + tid; lor < hi; lor += 1024) {
        const float p1x = lors[0 * NLORP + lor];
        const float p1y = lors[1 * NLORP + lor];
        const float p1z = lors[2 * NLORP + lor];
        const float dx  = lors[3 * NLORP + lor] - p1x;
        const float dy  = lors[4 * NLORP + lor] - p1y;
        float dz = lors[5 * NLORP + lor] - p1z;
        dz = (fabsf(dz) < 1e-6f) ? 1e-6f : dz;
        const float cfv = cf[lor];
        const float t  = (zc - p1z) / dz;
        const float xs = p1x + t * dx;
        const float ys = p1y + t * dy;
        const int i0 = (int)rintf((xs - XMIN) / VOX - 0.5f);
        const int j0 = (int)rintf((ys - XMIN) / VOX - 0.5f);
        const bool tin = (t >= 0.0f) && (t <= 1.0f);
        if (tin) {
            float ex[3], ey[3]; int ci[3], cj[3];
            axis_w(i0, xs, ex, ci);
            axis_w(j0, ys, ey, cj);
#pragma unroll
            for (int a = 0; a < 3; ++a) {
                const float wa = ex[a] * cfv;
                if (wa != 0.0f) {
#pragma unroll
                    for (int bo = 0; bo < 3; ++bo) {
                        const float w = wa * ey[bo];
                        if (w != 0.0f) atomicAdd(&pl[ci[a] * NG + cj[bo]], w);
                    }
                }
            }
        }
    }
    __syncthreads();

    float4* out4 = (float4*)(bpsub + ((size_t)sub * NG + k) * PLANE);
    const float4* s4 = (const float4*)pl;
    for (int i = tid; i < PLANE / 4; i += 1024) out4[i] = s4[i];
}

__global__ __launch_bounds__(256)
void finalize_kernel(const float* __restrict__ img, const float* __restrict__ eff,
                     float* __restrict__ out, int n)
{
    const int i = blockIdx.x * blockDim.x + threadIdx.x;
    if (i < n) out[i] = img[i] / (eff[i] + 1e-8f) * out[i];
}

extern "C" void kernel_launch(void* const* d_in, const int* in_sizes, int n_in,
                              void* d_out, int out_size, void* d_ws, size_t ws_size,
                              hipStream_t stream) {
    const float* image = (const float*)d_in[0];
    const float* eff   = (const float*)d_in[1];
    const float* xl    = (const float*)d_in[2];
    const float* yl    = (const float*)d_in[3];
    const float* zl    = (const float*)d_in[4];
    float* out = (float*)d_out;

    char* ws = (char*)d_ws;
    float* imgP  = (float*)(ws);                          //  8 MB [k][ii][jj]
    float* part  = (float*)(ws + 8388608ULL);             // 34.6 MB [k][lorp]
    float* bpsub = part;                                  // 32 MB alias (part dead in bp phase)
    float* cf    = (float*)(ws + 42991616ULL);            // 264 KB
    float* lorsR = (float*)(ws + 43261952ULL);            // 1.6 MB reordered [6][NLORP]
    int*   hist  = (int*)(ws + 44883968ULL);              // 4096
    int*   offA  = hist + 4096;
    int*   cnt   = hist + 8192;
    int*   base  = hist + 12288;                          // 33
    int*   rows  = base + 33;                             // 32
    int*   padb  = rows + 32;                             // 32
    const size_t zero_off = 43261952ULL;
    const size_t zero_sz  = 44883968ULL + (12288 + 33 + 32 + 32) * 4 - zero_off;

    hipMemsetAsync(out, 0, (size_t)out_size * sizeof(float), stream);

    const dim3 tb(32, 8), tg(4, 4, 128);
    const float* lin[3] = {zl, xl, yl};

    for (int pass = 0; pass < 3; ++pass) {
        const float* lsrc = lin[pass];
        // reorder this pass's LORs into lorsR
        hipMemsetAsync(ws + zero_off, 0, zero_sz, stream);
        sort_hist<<<64, 1024, 0, stream>>>(lsrc, hist);
        sort_scan<<<1, 1024, 0, stream>>>(hist, offA, base, rows, padb);
        sort_scatter<<<64, 1024, 0, stream>>>(lsrc, lorsR, offA, cnt, base, rows, padb);

        // image permute into this pass's [k][ii][jj] frame
        if (pass == 0)      permute_k<1, 16384, 128, 0, 1, false><<<tg, tb, 0, stream>>>(image, imgP); // z
        else if (pass == 1) permute_k<128, 1, 16384, 1, 1, false><<<tg, tb, 0, stream>>>(image, imgP); // x
        else                permute_k<1, 128, 16384, 0, 1, false><<<tg, tb, 0, stream>>>(image, imgP); // y

        plane_proj<<<256, 1024, 0, stream>>>(lorsR, imgP, part);
        reduce_cf<<<NLORP / 256, 256, 0, stream>>>(lorsR, part, cf);
        plane_bp<<<128 * NSUB, 1024, 0, stream>>>(lorsR, cf, bpsub);

        // accumulate into z-layout output, summing the NSUB sub-volumes
        if (pass == 0)      permute_k<128, 1, 16384, 1, NSUB, true><<<tg, tb, 0, stream>>>(bpsub, out);
        else if (pass == 1) permute_k<1, 16384, 128, 0, NSUB, true><<<tg, tb, 0, stream>>>(bpsub, out);
        else                permute_k<1, 128, 16384, 0, NSUB, true><<<tg, tb, 0, stream>>>(bpsub, out);
    }

    finalize_kernel<<<(out_size + 255) / 256, 256, 0, stream>>>(image, eff, out, out_size);
}

// Round 5
// 1413.149 us; speedup vs baseline: 1.0839x; 1.0839x over previous
//
#include <hip/hip_runtime.h>
#include <math.h>

#define NLOR  65536
#define NG    128
#define PLANE (NG * NG)
#define NSUB  4

#define VOX    1.671875f                 /* 214/128 exact */
#define XMIN  (-107.0f)
/* 1 / (2*sigma^2), sigma^2 = vox^2/pi  ->  inv = pi/(2*vox^2) */
#define INV2S2 ((float)(3.14159265358979323846 / (2.0 * (214.0/128.0) * (214.0/128.0))))

__device__ __forceinline__ void lor_geom(const float* __restrict__ lors, int lor,
    float& p1x, float& p1y, float& p1z,
    float& dx, float& dy, float& dz, float& dl)
{
    p1x = lors[0 * NLOR + lor];
    p1y = lors[1 * NLOR + lor];
    p1z = lors[2 * NLOR + lor];
    const float p2x = lors[3 * NLOR + lor];
    const float p2y = lors[4 * NLOR + lor];
    const float p2z = lors[5 * NLOR + lor];
    dx = p2x - p1x; dy = p2y - p1y;
    const float dz0 = p2z - p1z;
    const float L = sqrtf(dx * dx + dy * dy + dz0 * dz0);
    dz = (fabsf(dz0) < 1e-6f) ? 1e-6f : dz0;
    dl = VOX * L / fabsf(dz);
}

// separable clipped Gaussian row weights along one axis (branch-free).
// e[o] = w for offset o-1 (0 if that offset is out of bounds), c[o] = clipped idx
__device__ __forceinline__ void axis_w(int c0, float u, float* e, int* c)
{
#pragma unroll
    for (int o = 0; o < 3; ++o) {
        const int i  = c0 + o - 1;
        const int ic = min(max(i, 0), NG - 1);
        const float d = ((float)ic - u) * VOX;
        const float w = __expf(-d * d * INV2S2);
        e[o] = (i == ic) ? w : 0.0f;
        c[o] = ic;
    }
}

// ---------------------------------------------------------------------------
// Generic tiled 3D permute. Output layout is always ((P*128 + Q)*128 + R).
// Input address = P*SP + Q*SQ + R*SR (+ s*NG*PLANE for NSUM sub-buffers,
// summed). CONTIG: which of {P(0),Q(1)} has input stride 1.
// ---------------------------------------------------------------------------
template<int SP, int SQ, int SR, int CONTIG, int NSUM, bool ACCUM>
__global__ __launch_bounds__(256)
void permute_k(const float* __restrict__ in, float* __restrict__ out)
{
    __shared__ float tile[32][33];
    const int b  = blockIdx.z;
    const int c0 = blockIdx.x * 32;
    const int r0 = blockIdx.y * 32;
    const int tx = threadIdx.x, ty = threadIdx.y;

#pragma unroll
    for (int m = 0; m < 4; ++m) {
        const int C = c0 + tx;
        const int R = r0 + ty + 8 * m;
        const int P = (CONTIG == 0) ? C : b;
        const int Q = (CONTIG == 0) ? b : C;
        const int a = P * SP + Q * SQ + R * SR;
        float v = 0.0f;
#pragma unroll
        for (int s = 0; s < NSUM; ++s) v += in[a + s * NG * PLANE];
        tile[ty + 8 * m][tx] = v;
    }
    __syncthreads();
#pragma unroll
    for (int m = 0; m < 4; ++m) {
        const int R = r0 + tx;
        const int C = c0 + ty + 8 * m;
        const int P = (CONTIG == 0) ? C : b;
        const int Q = (CONTIG == 0) ? b : C;
        const int o = P * PLANE + Q * NG + R;
        if (ACCUM) out[o] += tile[tx][ty + 8 * m];
        else       out[o]  = tile[tx][ty + 8 * m];
    }
}

// ---------------------------------------------------------------------------
// Phase 1: per-(LOR, plane) projection partials. Image plane staged in LDS.
// ---------------------------------------------------------------------------
__global__ __launch_bounds__(1024)
void plane_proj(const float* __restrict__ lors, const float* __restrict__ imgP,
                float* __restrict__ part)
{
    __shared__ float pl[PLANE];
    const int k    = blockIdx.x >> 1;
    const int half = blockIdx.x & 1;
    const int tid  = threadIdx.x;

    const float4* src = (const float4*)(imgP + k * PLANE);
    float4* dst = (float4*)pl;
    for (int i = tid; i < PLANE / 4; i += 1024) dst[i] = src[i];
    __syncthreads();

    const float zc = XMIN + ((float)k + 0.5f) * VOX;
    const int lo = half * (NLOR / 2), hi = lo + NLOR / 2;
    for (int lor = lo + tid; lor < hi; lor += 1024) {
        float p1x, p1y, p1z, dx, dy, dz, dl;
        lor_geom(lors, lor, p1x, p1y, p1z, dx, dy, dz, dl);
        const float t  = (zc - p1z) / dz;
        const float xs = p1x + t * dx;
        const float ys = p1y + t * dy;
        const float u  = (xs - XMIN) / VOX - 0.5f;
        const float v  = (ys - XMIN) / VOX - 0.5f;
        const int i0 = (int)rintf(u);
        const int j0 = (int)rintf(v);
        const bool tin = (t >= 0.0f) && (t <= 1.0f);
        float ex[3], ey[3]; int ci[3], cj[3];
        axis_w(i0, u, ex, ci);
        axis_w(j0, v, ey, cj);
        float s = 0.0f;
#pragma unroll
        for (int a = 0; a < 3; ++a) {
            float r = 0.0f;
#pragma unroll
            for (int bo = 0; bo < 3; ++bo) r += ey[bo] * pl[ci[a] * NG + cj[bo]];
            s += ex[a] * r;
        }
        part[k * NLOR + lor] = tin ? s : 0.0f;
    }
}

// ---------------------------------------------------------------------------
// cf[lor] = dl / (dl * sum_k part + 1e-8)
// ---------------------------------------------------------------------------
__global__ __launch_bounds__(256)
void reduce_cf(const float* __restrict__ lors, const float* __restrict__ part,
               float* __restrict__ cf)
{
    const int lor = blockIdx.x * 256 + threadIdx.x;
    float s = 0.0f;
    for (int k = 0; k < NG; ++k) s += part[k * NLOR + lor];
    float p1x, p1y, p1z, dx, dy, dz, dl;
    lor_geom(lors, lor, p1x, p1y, p1z, dx, dy, dz, dl);
    const float proj = s * dl;
    cf[lor] = dl / (proj + 1e-8f);
}

// ---------------------------------------------------------------------------
// Phase 2: backprojection, fully branch-free inner loop. All 9 atomics
// execute unconditionally (masked lanes add 0.0); exec mask never changes.
// ---------------------------------------------------------------------------
__global__ __launch_bounds__(1024)
void plane_bp(const float* __restrict__ lors, const float* __restrict__ cf,
              float* __restrict__ bpsub)
{
    __shared__ float pl[PLANE];
    const int k   = blockIdx.x >> 2;
    const int sub = blockIdx.x & 3;
    const int tid = threadIdx.x;

    const float4 z4 = {0.0f, 0.0f, 0.0f, 0.0f};
    float4* dst = (float4*)pl;
    for (int i = tid; i < PLANE / 4; i += 1024) dst[i] = z4;
    __syncthreads();

    const float zc = XMIN + ((float)k + 0.5f) * VOX;
    const int lo = sub * (NLOR / NSUB), hi = lo + NLOR / NSUB;
    for (int lor = lo + tid; lor < hi; lor += 1024) {
        const float p1x = lors[0 * NLOR + lor];
        const float p1y = lors[1 * NLOR + lor];
        const float p1z = lors[2 * NLOR + lor];
        const float dx  = lors[3 * NLOR + lor] - p1x;
        const float dy  = lors[4 * NLOR + lor] - p1y;
        float dz = lors[5 * NLOR + lor] - p1z;
        dz = (fabsf(dz) < 1e-6f) ? 1e-6f : dz;
        const float t  = (zc - p1z) / dz;
        const float xs = p1x + t * dx;
        const float ys = p1y + t * dy;
        const float u  = (xs - XMIN) / VOX - 0.5f;
        const float v  = (ys - XMIN) / VOX - 0.5f;
        const int i0 = (int)rintf(u);
        const int j0 = (int)rintf(v);
        const bool tin = (t >= 0.0f) && (t <= 1.0f);
        float cfv = cf[lor];
        cfv = tin ? cfv : 0.0f;

        float ex[3], ey[3]; int ci[3], cj[3];
        axis_w(i0, u, ex, ci);
        axis_w(j0, v, ey, cj);

#pragma unroll
        for (int a = 0; a < 3; ++a) {
            const float wa = ex[a] * cfv;
            const int rowb = ci[a] * NG;
#pragma unroll
            for (int bo = 0; bo < 3; ++bo) {
                atomicAdd(&pl[rowb + cj[bo]], wa * ey[bo]);
            }
        }
    }
    __syncthreads();

    float4* out4 = (float4*)(bpsub + ((size_t)sub * NG + k) * PLANE);
    const float4* s4 = (const float4*)pl;
    for (int i = tid; i < PLANE / 4; i += 1024) out4[i] = s4[i];
}

__global__ __launch_bounds__(256)
void finalize_kernel(const float* __restrict__ img, const float* __restrict__ eff,
                     float* __restrict__ out, int n)
{
    const int i = blockIdx.x * blockDim.x + threadIdx.x;
    if (i < n) out[i] = img[i] / (eff[i] + 1e-8f) * out[i];
}

extern "C" void kernel_launch(void* const* d_in, const int* in_sizes, int n_in,
                              void* d_out, int out_size, void* d_ws, size_t ws_size,
                              hipStream_t stream) {
    const float* image = (const float*)d_in[0];
    const float* eff   = (const float*)d_in[1];
    const float* xl    = (const float*)d_in[2];
    const float* yl    = (const float*)d_in[3];
    const float* zl    = (const float*)d_in[4];
    float* out = (float*)d_out;

    char* ws = (char*)d_ws;
    float* imgP  = (float*)(ws);                       //  8 MB [k][ii][jj]
    float* part  = (float*)(ws + (size_t)( 8 << 20));  // 32 MB [k][lor]   (proj phase)
    float* bpsub = part;                               // 32 MB [sub][k][ii][jj] (bp phase)
    float* cf    = (float*)(ws + (size_t)(40 << 20));  // 256 KB [lor]

    hipMemsetAsync(out, 0, (size_t)out_size * sizeof(float), stream);

    const dim3 tb(32, 8), tg(4, 4, 128);

    // ---- z pass: (k,ii,jj) = (z,x,y); img strides (z:1, x:16384, y:128)
    permute_k<1, 16384, 128, 0, 1, false><<<tg, tb, 0, stream>>>(image, imgP);
    plane_proj<<<256, 1024, 0, stream>>>(zl, imgP, part);
    reduce_cf<<<256, 256, 0, stream>>>(zl, part, cf);
    plane_bp<<<128 * NSUB, 1024, 0, stream>>>(zl, cf, bpsub);
    // back: bp_z[z][x][y] -> out(x,y,z): in strides (x:128, y:1, z:16384), sum 4 subs
    permute_k<128, 1, 16384, 1, NSUB, true><<<tg, tb, 0, stream>>>(bpsub, out);

    // ---- x pass: (k,ii,jj) = (y,z,x); img strides (y:128, z:1, x:16384)
    permute_k<128, 1, 16384, 1, 1, false><<<tg, tb, 0, stream>>>(image, imgP);
    plane_proj<<<256, 1024, 0, stream>>>(xl, imgP, part);
    reduce_cf<<<256, 256, 0, stream>>>(xl, part, cf);
    plane_bp<<<128 * NSUB, 1024, 0, stream>>>(xl, cf, bpsub);
    // back: bp_x[y][z][x] -> out(x,y,z): in strides (x:1, y:16384, z:128), sum 4 subs
    permute_k<1, 16384, 128, 0, NSUB, true><<<tg, tb, 0, stream>>>(bpsub, out);

    // ---- y pass: (k,ii,jj) = (z,y,x); img strides (z:1, y:128, x:16384)
    permute_k<1, 128, 16384, 0, 1, false><<<tg, tb, 0, stream>>>(image, imgP);
    plane_proj<<<256, 1024, 0, stream>>>(yl, imgP, part);
    reduce_cf<<<256, 256, 0, stream>>>(yl, part, cf);
    plane_bp<<<128 * NSUB, 1024, 0, stream>>>(yl, cf, bpsub);
    // back: bp_y[z][y][x] -> out(x,y,z): in strides (x:1, y:128, z:16384), sum 4 subs
    permute_k<1, 128, 16384, 0, NSUB, true><<<tg, tb, 0, stream>>>(bpsub, out);

    finalize_kernel<<<(out_size + 255) / 256, 256, 0, stream>>>(image, eff, out, out_size);
}

// Round 6
// 416.757 us; speedup vs baseline: 3.6752x; 3.3908x over previous
//
#include <hip/hip_runtime.h>
#include <math.h>

#define NLOR  65536
#define NG    128
#define PLANE (NG * NG)
#define NSUB  4

#define VOX    1.671875f                 /* 214/128 exact */
#define XMIN  (-107.0f)
/* 1 / (2*sigma^2), sigma^2 = vox^2/pi  ->  inv = pi/(2*vox^2) */
#define INV2S2 ((float)(3.14159265358979323846 / (2.0 * (214.0/128.0) * (214.0/128.0))))

#define FPSCALE    8388608.0f            /* 2^23 fixed-point scale */
#define INVFPSCALE (1.0f / 8388608.0f)

__device__ __forceinline__ void lor_geom(const float* __restrict__ lors, int lor,
    float& p1x, float& p1y, float& p1z,
    float& dx, float& dy, float& dz, float& dl)
{
    p1x = lors[0 * NLOR + lor];
    p1y = lors[1 * NLOR + lor];
    p1z = lors[2 * NLOR + lor];
    const float p2x = lors[3 * NLOR + lor];
    const float p2y = lors[4 * NLOR + lor];
    const float p2z = lors[5 * NLOR + lor];
    dx = p2x - p1x; dy = p2y - p1y;
    const float dz0 = p2z - p1z;
    const float L = sqrtf(dx * dx + dy * dy + dz0 * dz0);
    dz = (fabsf(dz0) < 1e-6f) ? 1e-6f : dz0;
    dl = VOX * L / fabsf(dz);
}

// separable clipped Gaussian row weights along one axis (branch-free).
// e[o] = w for offset o-1 (0 if that offset is out of bounds), c[o] = clipped idx
__device__ __forceinline__ void axis_w(int c0, float u, float* e, int* c)
{
#pragma unroll
    for (int o = 0; o < 3; ++o) {
        const int i  = c0 + o - 1;
        const int ic = min(max(i, 0), NG - 1);
        const float d = ((float)ic - u) * VOX;
        const float w = __expf(-d * d * INV2S2);
        e[o] = (i == ic) ? w : 0.0f;
        c[o] = ic;
    }
}

// ---------------------------------------------------------------------------
// Generic tiled 3D permute. Output layout is always ((P*128 + Q)*128 + R).
// Input address = P*SP + Q*SQ + R*SR (+ s*NG*PLANE for NSUM sub-buffers,
// summed). CONTIG: which of {P(0),Q(1)} has input stride 1.
// ---------------------------------------------------------------------------
template<int SP, int SQ, int SR, int CONTIG, int NSUM, bool ACCUM>
__global__ __launch_bounds__(256)
void permute_k(const float* __restrict__ in, float* __restrict__ out)
{
    __shared__ float tile[32][33];
    const int b  = blockIdx.z;
    const int c0 = blockIdx.x * 32;
    const int r0 = blockIdx.y * 32;
    const int tx = threadIdx.x, ty = threadIdx.y;

#pragma unroll
    for (int m = 0; m < 4; ++m) {
        const int C = c0 + tx;
        const int R = r0 + ty + 8 * m;
        const int P = (CONTIG == 0) ? C : b;
        const int Q = (CONTIG == 0) ? b : C;
        const int a = P * SP + Q * SQ + R * SR;
        float v = 0.0f;
#pragma unroll
        for (int s = 0; s < NSUM; ++s) v += in[a + s * NG * PLANE];
        tile[ty + 8 * m][tx] = v;
    }
    __syncthreads();
#pragma unroll
    for (int m = 0; m < 4; ++m) {
        const int R = r0 + tx;
        const int C = c0 + ty + 8 * m;
        const int P = (CONTIG == 0) ? C : b;
        const int Q = (CONTIG == 0) ? b : C;
        const int o = P * PLANE + Q * NG + R;
        if (ACCUM) out[o] += tile[tx][ty + 8 * m];
        else       out[o]  = tile[tx][ty + 8 * m];
    }
}

// ---------------------------------------------------------------------------
// Phase 1: per-(LOR, plane) projection partials. Image plane staged in LDS.
// ---------------------------------------------------------------------------
__global__ __launch_bounds__(1024)
void plane_proj(const float* __restrict__ lors, const float* __restrict__ imgP,
                float* __restrict__ part)
{
    __shared__ float pl[PLANE];
    const int k    = blockIdx.x >> 1;
    const int half = blockIdx.x & 1;
    const int tid  = threadIdx.x;

    const float4* src = (const float4*)(imgP + k * PLANE);
    float4* dst = (float4*)pl;
    for (int i = tid; i < PLANE / 4; i += 1024) dst[i] = src[i];
    __syncthreads();

    const float zc = XMIN + ((float)k + 0.5f) * VOX;
    const int lo = half * (NLOR / 2), hi = lo + NLOR / 2;
    for (int lor = lo + tid; lor < hi; lor += 1024) {
        float p1x, p1y, p1z, dx, dy, dz, dl;
        lor_geom(lors, lor, p1x, p1y, p1z, dx, dy, dz, dl);
        const float t  = (zc - p1z) / dz;
        const float xs = p1x + t * dx;
        const float ys = p1y + t * dy;
        const float u  = (xs - XMIN) / VOX - 0.5f;
        const float v  = (ys - XMIN) / VOX - 0.5f;
        const int i0 = (int)rintf(u);
        const int j0 = (int)rintf(v);
        const bool tin = (t >= 0.0f) && (t <= 1.0f);
        float ex[3], ey[3]; int ci[3], cj[3];
        axis_w(i0, u, ex, ci);
        axis_w(j0, v, ey, cj);
        float s = 0.0f;
#pragma unroll
        for (int a = 0; a < 3; ++a) {
            float r = 0.0f;
#pragma unroll
            for (int bo = 0; bo < 3; ++bo) r += ey[bo] * pl[ci[a] * NG + cj[bo]];
            s += ex[a] * r;
        }
        part[k * NLOR + lor] = tin ? s : 0.0f;
    }
}

// ---------------------------------------------------------------------------
// cf[lor] = dl / (dl * sum_k part + 1e-8)
// ---------------------------------------------------------------------------
__global__ __launch_bounds__(256)
void reduce_cf(const float* __restrict__ lors, const float* __restrict__ part,
               float* __restrict__ cf)
{
    const int lor = blockIdx.x * 256 + threadIdx.x;
    float s = 0.0f;
    for (int k = 0; k < NG; ++k) s += part[k * NLOR + lor];
    float p1x, p1y, p1z, dx, dy, dz, dl;
    lor_geom(lors, lor, p1x, p1y, p1z, dx, dy, dz, dl);
    const float proj = s * dl;
    cf[lor] = dl / (proj + 1e-8f);
}

// ---------------------------------------------------------------------------
// Phase 2: backprojection with 64-bit packed fixed-point LDS atomics.
// Plane = 128 rows x 64 u64 pairs; each pair holds two 2^-23 fixed-point
// accumulators. A 3-cell row deposit = 2 u64 atomics -> 6 ops/LOR*plane
// instead of 9. OOB cells have zero weight, so clamped pair addrs are safe.
// ---------------------------------------------------------------------------
__global__ __launch_bounds__(1024)
void plane_bp(const float* __restrict__ lors, const float* __restrict__ cf,
              float* __restrict__ bpsub)
{
    __shared__ unsigned long long pl[NG * 64];
    const int k   = blockIdx.x >> 2;
    const int sub = blockIdx.x & 3;
    const int tid = threadIdx.x;

    for (int i = tid; i < NG * 64; i += 1024) pl[i] = 0ULL;
    __syncthreads();

    const float zc = XMIN + ((float)k + 0.5f) * VOX;
    const int lo = sub * (NLOR / NSUB), hi = lo + NLOR / NSUB;
    for (int lor = lo + tid; lor < hi; lor += 1024) {
        const float p1x = lors[0 * NLOR + lor];
        const float p1y = lors[1 * NLOR + lor];
        const float p1z = lors[2 * NLOR + lor];
        const float dx  = lors[3 * NLOR + lor] - p1x;
        const float dy  = lors[4 * NLOR + lor] - p1y;
        float dz = lors[5 * NLOR + lor] - p1z;
        dz = (fabsf(dz) < 1e-6f) ? 1e-6f : dz;
        const float t  = (zc - p1z) / dz;
        const float xs = p1x + t * dx;
        const float ys = p1y + t * dy;
        const float u  = (xs - XMIN) / VOX - 0.5f;
        const float v  = (ys - XMIN) / VOX - 0.5f;
        const int i0 = (int)rintf(u);
        const int j0 = (int)rintf(v);
        const bool tin = (t >= 0.0f) && (t <= 1.0f);
        float cfv = cf[lor];
        cfv = tin ? cfv : 0.0f;

        float ex[3], ey[3]; int ci[3], cj[3];
        axis_w(i0, u, ex, ci);
        axis_w(j0, v, ey, cj);

        // route the 3 j-weights into two aligned pairs by parity of j0
        const int odd = j0 & 1;
        const float lA = odd ? ey[0] : 0.0f;
        const float hA = odd ? ey[1] : ey[0];
        const float lB = odd ? ey[2] : ey[1];
        const float hB = odd ? 0.0f  : ey[2];
        const int p0 = (j0 - 1) >> 1;
        const int pA = min(max(p0,     0), 63);
        const int pB = min(max(p0 + 1, 0), 63);

#pragma unroll
        for (int a = 0; a < 3; ++a) {
            const float wa = ex[a] * cfv * FPSCALE;
            const int rowb = ci[a] << 6;
            const unsigned long long vA =
                ((unsigned long long)(unsigned)(wa * hA) << 32) |
                 (unsigned long long)(unsigned)(wa * lA);
            const unsigned long long vB =
                ((unsigned long long)(unsigned)(wa * hB) << 32) |
                 (unsigned long long)(unsigned)(wa * lB);
            atomicAdd(&pl[rowb + pA], vA);
            atomicAdd(&pl[rowb + pB], vB);
        }
    }
    __syncthreads();

    float2* out2 = (float2*)(bpsub + ((size_t)sub * NG + k) * PLANE);
    for (int i = tid; i < NG * 64; i += 1024) {
        const unsigned long long vv = pl[i];
        out2[i] = make_float2((float)(unsigned)(vv & 0xffffffffULL) * INVFPSCALE,
                              (float)(unsigned)(vv >> 32) * INVFPSCALE);
    }
}

__global__ __launch_bounds__(256)
void finalize_kernel(const float* __restrict__ img, const float* __restrict__ eff,
                     float* __restrict__ out, int n)
{
    const int i = blockIdx.x * blockDim.x + threadIdx.x;
    if (i < n) out[i] = img[i] / (eff[i] + 1e-8f) * out[i];
}

extern "C" void kernel_launch(void* const* d_in, const int* in_sizes, int n_in,
                              void* d_out, int out_size, void* d_ws, size_t ws_size,
                              hipStream_t stream) {
    const float* image = (const float*)d_in[0];
    const float* eff   = (const float*)d_in[1];
    const float* xl    = (const float*)d_in[2];
    const float* yl    = (const float*)d_in[3];
    const float* zl    = (const float*)d_in[4];
    float* out = (float*)d_out;

    char* ws = (char*)d_ws;
    float* imgP  = (float*)(ws);                       //  8 MB [k][ii][jj]
    float* part  = (float*)(ws + (size_t)( 8 << 20));  // 32 MB [k][lor]   (proj phase)
    float* bpsub = part;                               // 32 MB [sub][k][ii][jj] (bp phase)
    float* cf    = (float*)(ws + (size_t)(40 << 20));  // 256 KB [lor]

    hipMemsetAsync(out, 0, (size_t)out_size * sizeof(float), stream);

    const dim3 tb(32, 8), tg(4, 4, 128);

    // ---- z pass: (k,ii,jj) = (z,x,y); img strides (z:1, x:16384, y:128)
    permute_k<1, 16384, 128, 0, 1, false><<<tg, tb, 0, stream>>>(image, imgP);
    plane_proj<<<256, 1024, 0, stream>>>(zl, imgP, part);
    reduce_cf<<<256, 256, 0, stream>>>(zl, part, cf);
    plane_bp<<<128 * NSUB, 1024, 0, stream>>>(zl, cf, bpsub);
    // back: bp_z[z][x][y] -> out(x,y,z): in strides (x:128, y:1, z:16384), sum 4 subs
    permute_k<128, 1, 16384, 1, NSUB, true><<<tg, tb, 0, stream>>>(bpsub, out);

    // ---- x pass: (k,ii,jj) = (y,z,x); img strides (y:128, z:1, x:16384)
    permute_k<128, 1, 16384, 1, 1, false><<<tg, tb, 0, stream>>>(image, imgP);
    plane_proj<<<256, 1024, 0, stream>>>(xl, imgP, part);
    reduce_cf<<<256, 256, 0, stream>>>(xl, part, cf);
    plane_bp<<<128 * NSUB, 1024, 0, stream>>>(xl, cf, bpsub);
    // back: bp_x[y][z][x] -> out(x,y,z): in strides (x:1, y:16384, z:128), sum 4 subs
    permute_k<1, 16384, 128, 0, NSUB, true><<<tg, tb, 0, stream>>>(bpsub, out);

    // ---- y pass: (k,ii,jj) = (z,y,x); img strides (z:1, y:128, x:16384)
    permute_k<1, 128, 16384, 0, 1, false><<<tg, tb, 0, stream>>>(image, imgP);
    plane_proj<<<256, 1024, 0, stream>>>(yl, imgP, part);
    reduce_cf<<<256, 256, 0, stream>>>(yl, part, cf);
    plane_bp<<<128 * NSUB, 1024, 0, stream>>>(yl, cf, bpsub);
    // back: bp_y[z][y][x] -> out(x,y,z): in strides (x:1, y:128, z:16384), sum 4 subs
    permute_k<1, 128, 16384, 0, NSUB, true><<<tg, tb, 0, stream>>>(bpsub, out);

    finalize_kernel<<<(out_size + 255) / 256, 256, 0, stream>>>(image, eff, out, out_size);
}

// Round 8
// 380.729 us; speedup vs baseline: 4.0230x; 1.0946x over previous
//
#include <hip/hip_runtime.h>
#include <math.h>

#define NLOR  65536
#define NG    128
#define PLANE (NG * NG)
#define NSUB  4
#define KG    8               /* planes per proj block */
#define NKG   (NG / KG)       /* 16 plane groups */

#define VOX    1.671875f                 /* 214/128 exact */
#define XMIN  (-107.0f)
#define INV2S2 ((float)(3.14159265358979323846 / (2.0 * (214.0/128.0) * (214.0/128.0))))

#define FPSCALE    8388608.0f            /* 2^23 fixed-point scale */
#define INVFPSCALE (1.0f / 8388608.0f)

// separable clipped Gaussian row weights along one axis (branch-free).
__device__ __forceinline__ void axis_w(int c0, float u, float* e, int* c)
{
#pragma unroll
    for (int o = 0; o < 3; ++o) {
        const int i  = c0 + o - 1;
        const int ic = min(max(i, 0), NG - 1);
        const float d = ((float)ic - u) * VOX;
        const float w = __expf(-d * d * INV2S2);
        e[o] = (i == ic) ? w : 0.0f;
        c[o] = ic;
    }
}

// route 3 j-weights into two aligned pairs by parity of j0
__device__ __forceinline__ void route_j(int j0, const float* ey,
    float& lA, float& hA, float& lB, float& hB, int& pA, int& pB)
{
    const int odd = j0 & 1;
    lA = odd ? ey[0] : 0.0f;
    hA = odd ? ey[1] : ey[0];
    lB = odd ? ey[2] : ey[1];
    hB = odd ? 0.0f  : ey[2];
    const int p0 = (j0 - 1) >> 1;
    pA = min(max(p0,     0), 63);
    pB = min(max(p0 + 1, 0), 63);
}

// ---------------------------------------------------------------------------
// Generic tiled 3D permute; optional NSUM-subvolume sum, accumulate, and
// fused final epilogue out = img/(eff+1e-8)*(out + v).
// ---------------------------------------------------------------------------
template<int SP, int SQ, int SR, int CONTIG, int NSUM, bool ACCUM, bool FINAL>
__global__ __launch_bounds__(256)
void permute_k(const float* __restrict__ in, float* __restrict__ out,
               const float* __restrict__ img, const float* __restrict__ eff)
{
    __shared__ float tile[32][33];
    const int b  = blockIdx.z;
    const int c0 = blockIdx.x * 32;
    const int r0 = blockIdx.y * 32;
    const int tx = threadIdx.x, ty = threadIdx.y;

#pragma unroll
    for (int m = 0; m < 4; ++m) {
        const int C = c0 + tx;
        const int R = r0 + ty + 8 * m;
        const int P = (CONTIG == 0) ? C : b;
        const int Q = (CONTIG == 0) ? b : C;
        const int a = P * SP + Q * SQ + R * SR;
        float v = 0.0f;
#pragma unroll
        for (int s = 0; s < NSUM; ++s) v += in[a + s * NG * PLANE];
        tile[ty + 8 * m][tx] = v;
    }
    __syncthreads();
#pragma unroll
    for (int m = 0; m < 4; ++m) {
        const int R = r0 + tx;
        const int C = c0 + ty + 8 * m;
        const int P = (CONTIG == 0) ? C : b;
        const int Q = (CONTIG == 0) ? b : C;
        const int o = P * PLANE + Q * NG + R;
        float v = tile[tx][ty + 8 * m];
        if (ACCUM) v += out[o];
        if (FINAL) v = img[o] / (eff[o] + 1e-8f) * v;
        out[o] = v;
    }
}

// ---------------------------------------------------------------------------
// Phase 1: projection. Each block owns KG=8 consecutive planes (staged one at
// a time in LDS as float2 pairs) x a 2048-LOR chunk; per-LOR partial sums
// accumulate in registers across the 8 planes -> part8[g][lor] (4 MB).
// Row reads are 2x ds_read_b64 instead of 3x ds_read_b32.
// ---------------------------------------------------------------------------
__global__ __launch_bounds__(1024)
void plane_proj(const float* __restrict__ lors, const float* __restrict__ imgP,
                float* __restrict__ part8)
{
    __shared__ float2 pl2[NG * 64];
    const int chunk = blockIdx.x;          // 32 chunks x 2048 LORs
    const int g     = blockIdx.y;          // 16 plane groups
    const int tid   = threadIdx.x;
    const int lor0  = chunk * 2048 + tid;  // this thread's LORs: lor0, lor0+1024
    float s0 = 0.0f, s1 = 0.0f;

    for (int st = 0; st < KG; ++st) {
        const int k = g * KG + st;
        const float4* src = (const float4*)(imgP + k * PLANE);
        float4* dst = (float4*)pl2;
        for (int i = tid; i < PLANE / 4; i += 1024) dst[i] = src[i];
        __syncthreads();

        const float zc = XMIN + ((float)k + 0.5f) * VOX;
#pragma unroll
        for (int l = 0; l < 2; ++l) {
            const int lor = lor0 + l * 1024;
            const float p1x = lors[0 * NLOR + lor];
            const float p1y = lors[1 * NLOR + lor];
            const float p1z = lors[2 * NLOR + lor];
            const float dx  = lors[3 * NLOR + lor] - p1x;
            const float dy  = lors[4 * NLOR + lor] - p1y;
            float dz = lors[5 * NLOR + lor] - p1z;
            dz = (fabsf(dz) < 1e-6f) ? 1e-6f : dz;
            const float t  = (zc - p1z) / dz;
            const float xs = p1x + t * dx;
            const float ys = p1y + t * dy;
            const float u  = (xs - XMIN) / VOX - 0.5f;
            const float v  = (ys - XMIN) / VOX - 0.5f;
            const int i0 = (int)rintf(u);
            const int j0 = (int)rintf(v);
            const bool tin = (t >= 0.0f) && (t <= 1.0f);
            float ex[3], ey[3]; int ci[3], cj[3];
            axis_w(i0, u, ex, ci);
            axis_w(j0, v, ey, cj);
            float lA, hA, lB, hB; int pA, pB;
            route_j(j0, ey, lA, hA, lB, hB, pA, pB);
            float acc = 0.0f;
#pragma unroll
            for (int a = 0; a < 3; ++a) {
                const int rowb = ci[a] << 6;
                const float2 A = pl2[rowb + pA];
                const float2 B = pl2[rowb + pB];
                acc += ex[a] * (lA * A.x + hA * A.y + lB * B.x + hB * B.y);
            }
            const float add = tin ? acc : 0.0f;
            if (l == 0) s0 += add; else s1 += add;
        }
        __syncthreads();
    }
    part8[g * NLOR + lor0]        = s0;
    part8[g * NLOR + lor0 + 1024] = s1;
}

// ---------------------------------------------------------------------------
// cf[lor] = dl / (dl * sum_g part8 + 1e-8)
// ---------------------------------------------------------------------------
__global__ __launch_bounds__(256)
void reduce_cf(const float* __restrict__ lors, const float* __restrict__ part8,
               float* __restrict__ cf)
{
    const int lor = blockIdx.x * 256 + threadIdx.x;
    float s = 0.0f;
#pragma unroll
    for (int g = 0; g < NKG; ++g) s += part8[g * NLOR + lor];

    const float p1x = lors[0 * NLOR + lor];
    const float p1y = lors[1 * NLOR + lor];
    const float p1z = lors[2 * NLOR + lor];
    const float dx  = lors[3 * NLOR + lor] - p1x;
    const float dy  = lors[4 * NLOR + lor] - p1y;
    const float dz0 = lors[5 * NLOR + lor] - p1z;
    const float L = sqrtf(dx * dx + dy * dy + dz0 * dz0);
    const float adz = fmaxf(fabsf(dz0), 1e-6f);
    const float dl = VOX * L / adz;
    cf[lor] = dl / (s * dl + 1e-8f);
}

// ---------------------------------------------------------------------------
// Phase 2: backprojection with 64-bit packed fixed-point LDS atomics
// (native ds_add_u64). 6 atomics per LOR*plane.
// ---------------------------------------------------------------------------
__global__ __launch_bounds__(1024)
void plane_bp(const float* __restrict__ lors, const float* __restrict__ cf,
              float* __restrict__ bpsub)
{
    __shared__ unsigned long long pl[NG * 64];
    const int k   = blockIdx.x >> 2;
    const int sub = blockIdx.x & 3;
    const int tid = threadIdx.x;

    for (int i = tid; i < NG * 64; i += 1024) pl[i] = 0ULL;
    __syncthreads();

    const float zc = XMIN + ((float)k + 0.5f) * VOX;
    const int lo = sub * (NLOR / NSUB), hi = lo + NLOR / NSUB;
    for (int lor = lo + tid; lor < hi; lor += 1024) {
        const float p1x = lors[0 * NLOR + lor];
        const float p1y = lors[1 * NLOR + lor];
        const float p1z = lors[2 * NLOR + lor];
        const float dx  = lors[3 * NLOR + lor] - p1x;
        const float dy  = lors[4 * NLOR + lor] - p1y;
        float dz = lors[5 * NLOR + lor] - p1z;
        dz = (fabsf(dz) < 1e-6f) ? 1e-6f : dz;
        const float t  = (zc - p1z) / dz;
        const float xs = p1x + t * dx;
        const float ys = p1y + t * dy;
        const float u  = (xs - XMIN) / VOX - 0.5f;
        const float v  = (ys - XMIN) / VOX - 0.5f;
        const int i0 = (int)rintf(u);
        const int j0 = (int)rintf(v);
        const bool tin = (t >= 0.0f) && (t <= 1.0f);
        float cfv = cf[lor];
        cfv = tin ? cfv : 0.0f;

        float ex[3], ey[3]; int ci[3], cj[3];
        axis_w(i0, u, ex, ci);
        axis_w(j0, v, ey, cj);
        float lA, hA, lB, hB; int pA, pB;
        route_j(j0, ey, lA, hA, lB, hB, pA, pB);

#pragma unroll
        for (int a = 0; a < 3; ++a) {
            const float wa = ex[a] * cfv * FPSCALE;
            const int rowb = ci[a] << 6;
            const unsigned long long vA =
                ((unsigned long long)(unsigned)(wa * hA) << 32) |
                 (unsigned long long)(unsigned)(wa * lA);
            const unsigned long long vB =
                ((unsigned long long)(unsigned)(wa * hB) << 32) |
                 (unsigned long long)(unsigned)(wa * lB);
            atomicAdd(&pl[rowb + pA], vA);
            atomicAdd(&pl[rowb + pB], vB);
        }
    }
    __syncthreads();

    float2* out2 = (float2*)(bpsub + ((size_t)sub * NG + k) * PLANE);
    for (int i = tid; i < NG * 64; i += 1024) {
        const unsigned long long vv = pl[i];
        out2[i] = make_float2((float)(unsigned)(vv & 0xffffffffULL) * INVFPSCALE,
                              (float)(unsigned)(vv >> 32) * INVFPSCALE);
    }
}

extern "C" void kernel_launch(void* const* d_in, const int* in_sizes, int n_in,
                              void* d_out, int out_size, void* d_ws, size_t ws_size,
                              hipStream_t stream) {
    const float* image = (const float*)d_in[0];
    const float* eff   = (const float*)d_in[1];
    const float* xl    = (const float*)d_in[2];
    const float* yl    = (const float*)d_in[3];
    const float* zl    = (const float*)d_in[4];
    float* out = (float*)d_out;

    char* ws = (char*)d_ws;
    float* imgP  = (float*)(ws);                       //  8 MB [k][ii][jj]
    float* bpsub = (float*)(ws + (size_t)( 8 << 20));  // 32 MB [sub][k][ii][jj]
    float* part8 = (float*)(ws + (size_t)(40 << 20));  //  4 MB [g][lor]
    float* cf    = (float*)(ws + (size_t)(44 << 20));  // 256 KB [lor]

    const dim3 tb(32, 8), tg(4, 4, 128);
    const dim3 pg(32, 16);   // proj: 32 LOR chunks x 16 plane groups

    // ---- z pass: (k,ii,jj) = (z,x,y)
    permute_k<1, 16384, 128, 0, 1, false, false><<<tg, tb, 0, stream>>>(image, imgP, nullptr, nullptr);
    plane_proj<<<pg, 1024, 0, stream>>>(zl, imgP, part8);
    reduce_cf<<<256, 256, 0, stream>>>(zl, part8, cf);
    plane_bp<<<128 * NSUB, 1024, 0, stream>>>(zl, cf, bpsub);
    // bp_z[z][x][y] -> out(x,y,z), first pass overwrites (no memset needed)
    permute_k<128, 1, 16384, 1, NSUB, false, false><<<tg, tb, 0, stream>>>(bpsub, out, nullptr, nullptr);

    // ---- x pass: (k,ii,jj) = (y,z,x)
    permute_k<128, 1, 16384, 1, 1, false, false><<<tg, tb, 0, stream>>>(image, imgP, nullptr, nullptr);
    plane_proj<<<pg, 1024, 0, stream>>>(xl, imgP, part8);
    reduce_cf<<<256, 256, 0, stream>>>(xl, part8, cf);
    plane_bp<<<128 * NSUB, 1024, 0, stream>>>(xl, cf, bpsub);
    permute_k<1, 16384, 128, 0, NSUB, true, false><<<tg, tb, 0, stream>>>(bpsub, out, nullptr, nullptr);

    // ---- y pass: (k,ii,jj) = (z,y,x); final permute fuses img/(eff+eps)*
    permute_k<1, 128, 16384, 0, 1, false, false><<<tg, tb, 0, stream>>>(image, imgP, nullptr, nullptr);
    plane_proj<<<pg, 1024, 0, stream>>>(yl, imgP, part8);
    reduce_cf<<<256, 256, 0, stream>>>(yl, part8, cf);
    plane_bp<<<128 * NSUB, 1024, 0, stream>>>(yl, cf, bpsub);
    permute_k<1, 128, 16384, 0, NSUB, true, true><<<tg, tb, 0, stream>>>(bpsub, out, image, eff);
}

// Round 10
// 310.430 us; speedup vs baseline: 4.9340x; 1.2265x over previous
//
#include <hip/hip_runtime.h>
#include <math.h>

#define NLOR  65536
#define NG    128
#define PLANE (NG * NG)
#define NSUB  4
#define KG    8               /* planes per proj block */
#define NKG   (NG / KG)       /* 16 plane groups */

#define VOX    1.671875f                 /* 214/128 exact */
#define XMIN  (-107.0f)
/* weight arg in cell units: (m+d)^2 * VOX^2 * pi/(2*VOX^2) = (pi/2)(m+d)^2 */
#define C2     1.57079632679f

#define FPSCALE    8388608.0f            /* 2^23 fixed-point scale */
#define INVFPSCALE (1.0f / 8388608.0f)

// ---------------------------------------------------------------------------
// Generic tiled 3D permute; optional NSUM-subvolume sum, accumulate, and
// fused final epilogue out = img/(eff+1e-8)*(out + v).
// ---------------------------------------------------------------------------
template<int SP, int SQ, int SR, int CONTIG, int NSUM, bool ACCUM, bool FINAL>
__global__ __launch_bounds__(256)
void permute_k(const float* __restrict__ in, float* __restrict__ out,
               const float* __restrict__ img, const float* __restrict__ eff)
{
    __shared__ float tile[32][33];
    const int b  = blockIdx.z;
    const int c0 = blockIdx.x * 32;
    const int r0 = blockIdx.y * 32;
    const int tx = threadIdx.x, ty = threadIdx.y;

#pragma unroll
    for (int m = 0; m < 4; ++m) {
        const int C = c0 + tx;
        const int R = r0 + ty + 8 * m;
        const int P = (CONTIG == 0) ? C : b;
        const int Q = (CONTIG == 0) ? b : C;
        const int a = P * SP + Q * SQ + R * SR;
        float v = 0.0f;
#pragma unroll
        for (int s = 0; s < NSUM; ++s) v += in[a + s * NG * PLANE];
        tile[ty + 8 * m][tx] = v;
    }
    __syncthreads();
#pragma unroll
    for (int m = 0; m < 4; ++m) {
        const int R = r0 + tx;
        const int C = c0 + ty + 8 * m;
        const int P = (CONTIG == 0) ? C : b;
        const int Q = (CONTIG == 0) ? b : C;
        const int o = P * PLANE + Q * NG + R;
        float v = tile[tx][ty + 8 * m];
        if (ACCUM) v += out[o];
        if (FINAL) v = img[o] / (eff[o] + 1e-8f) * v;
        out[o] = v;
    }
}

// ---------------------------------------------------------------------------
// Phase 1: projection. Block = (2048-LOR chunk) x (8-plane group). LOR data
// loaded ONCE per block; u,v,t are affine in plane index k -> per plane just
// 3 fma + 2 rintf. No per-cell bounds masks: input geometry guarantees the
// 3x3 footprint is in-bounds whenever t is in range (transverse endpoints
// span +-96.3 vs grid +-107); t-masked lanes are zeroed at accumulate and
// their (clamped) addresses are harmless reads.
// ---------------------------------------------------------------------------
__global__ __launch_bounds__(1024)
void plane_proj(const float* __restrict__ lors, const float* __restrict__ imgP,
                float* __restrict__ part8)
{
    __shared__ float2 pl2[NG * 64];
    const int chunk = blockIdx.x;          // 32 chunks x 2048 LORs
    const int g     = blockIdx.y;          // 16 plane groups
    const int tid   = threadIdx.x;
    const int lor0  = chunk * 2048 + tid;  // this thread's LORs: lor0, lor0+1024

    float tA[2], uA[2], vA[2], dtA[2], duA[2], dvA[2], sA[2];
#pragma unroll
    for (int l = 0; l < 2; ++l) {
        const int lor = lor0 + l * 1024;
        const float p1x = lors[0 * NLOR + lor];
        const float p1y = lors[1 * NLOR + lor];
        const float p1z = lors[2 * NLOR + lor];
        const float dx  = lors[3 * NLOR + lor] - p1x;
        const float dy  = lors[4 * NLOR + lor] - p1y;
        float dz = lors[5 * NLOR + lor] - p1z;
        dz = (fabsf(dz) < 1e-6f) ? 1e-6f : dz;
        const float rdz = 1.0f / dz;
        const float zc0 = XMIN + ((float)(g * KG) + 0.5f) * VOX;
        tA[l]  = (zc0 - p1z) * rdz;
        dtA[l] = VOX * rdz;
        uA[l]  = (fmaf(tA[l], dx, p1x) - XMIN) * (1.0f / VOX) - 0.5f;
        vA[l]  = (fmaf(tA[l], dy, p1y) - XMIN) * (1.0f / VOX) - 0.5f;
        duA[l] = dx * rdz;                 /* = dt*dx/VOX */
        dvA[l] = dy * rdz;
        sA[l]  = 0.0f;
    }

    for (int st = 0; st < KG; ++st) {
        const int k = g * KG + st;
        const float4* src = (const float4*)(imgP + k * PLANE);
        float4* dst = (float4*)pl2;
        for (int i = tid; i < PLANE / 4; i += 1024) dst[i] = src[i];
        __syncthreads();

        const float fst = (float)st;
#pragma unroll
        for (int l = 0; l < 2; ++l) {
            const float t = fmaf(fst, dtA[l], tA[l]);
            const float u = fmaf(fst, duA[l], uA[l]);
            const float v = fmaf(fst, dvA[l], vA[l]);
            const int i0 = (int)rintf(u);
            const int j0 = (int)rintf(v);
            const float mi = (float)i0 - u;     /* in [-0.5, 0.5] */
            const float mj = (float)j0 - v;
            const float mim = mi - 1.0f, mip = mi + 1.0f;
            const float mjm = mj - 1.0f, mjp = mj + 1.0f;
            const float exm = __expf(-C2 * mim * mim);
            const float ex0 = __expf(-C2 * mi  * mi );
            const float exq = __expf(-C2 * mip * mip);
            const float eym = __expf(-C2 * mjm * mjm);
            const float ey0 = __expf(-C2 * mj  * mj );
            const float eyq = __expf(-C2 * mjp * mjp);

            const int odd = j0 & 1;
            const float lA = odd ? eym : 0.0f;
            const float hA = odd ? ey0 : eym;
            const float lB = odd ? eyq : ey0;
            const float hB = odd ? 0.0f : eyq;
            const int p0 = min(max((j0 - 1) >> 1, 0), 62);
            const int ib = min(max(i0 - 1, 0), 125);

            const float exv[3] = {exm, ex0, exq};
            float acc = 0.0f;
#pragma unroll
            for (int a = 0; a < 3; ++a) {
                const int rowb = (ib + a) << 6;
                const float2 A = pl2[rowb + p0];
                const float2 B = pl2[rowb + p0 + 1];
                acc += exv[a] * (lA * A.x + hA * A.y + lB * B.x + hB * B.y);
            }
            const bool tin = (t >= 0.0f) && (t <= 1.0f);
            sA[l] += tin ? acc : 0.0f;
        }
        __syncthreads();
    }
    part8[g * NLOR + lor0]        = sA[0];
    part8[g * NLOR + lor0 + 1024] = sA[1];
}

// ---------------------------------------------------------------------------
// cf[lor] = dl / (dl * sum_g part8 + 1e-8)
// ---------------------------------------------------------------------------
__global__ __launch_bounds__(256)
void reduce_cf(const float* __restrict__ lors, const float* __restrict__ part8,
               float* __restrict__ cf)
{
    const int lor = blockIdx.x * 256 + threadIdx.x;
    float s = 0.0f;
#pragma unroll
    for (int g = 0; g < NKG; ++g) s += part8[g * NLOR + lor];

    const float p1x = lors[0 * NLOR + lor];
    const float p1y = lors[1 * NLOR + lor];
    const float p1z = lors[2 * NLOR + lor];
    const float dx  = lors[3 * NLOR + lor] - p1x;
    const float dy  = lors[4 * NLOR + lor] - p1y;
    const float dz0 = lors[5 * NLOR + lor] - p1z;
    const float L = sqrtf(dx * dx + dy * dy + dz0 * dz0);
    const float adz = fmaxf(fabsf(dz0), 1e-6f);
    const float dl = VOX * L / adz;
    cf[lor] = dl / (s * dl + 1e-8f);
}

// ---------------------------------------------------------------------------
// Phase 2: backprojection with 64-bit packed fixed-point LDS atomics
// (native ds_add_u64). 6 atomics per LOR*plane; same mask-free weight path
// as proj (t-masked lanes fold cfv=0 into all deposits).
// ---------------------------------------------------------------------------
__global__ __launch_bounds__(1024)
void plane_bp(const float* __restrict__ lors, const float* __restrict__ cf,
              float* __restrict__ bpsub)
{
    __shared__ unsigned long long pl[NG * 64];
    const int k   = blockIdx.x >> 2;
    const int sub = blockIdx.x & 3;
    const int tid = threadIdx.x;

    for (int i = tid; i < NG * 64; i += 1024) pl[i] = 0ULL;
    __syncthreads();

    const float zc = XMIN + ((float)k + 0.5f) * VOX;
    const int lo = sub * (NLOR / NSUB), hi = lo + NLOR / NSUB;
    for (int lor = lo + tid; lor < hi; lor += 1024) {
        const float p1x = lors[0 * NLOR + lor];
        const float p1y = lors[1 * NLOR + lor];
        const float p1z = lors[2 * NLOR + lor];
        const float dx  = lors[3 * NLOR + lor] - p1x;
        const float dy  = lors[4 * NLOR + lor] - p1y;
        float dz = lors[5 * NLOR + lor] - p1z;
        dz = (fabsf(dz) < 1e-6f) ? 1e-6f : dz;
        const float t  = (zc - p1z) / dz;
        const float u  = (fmaf(t, dx, p1x) - XMIN) * (1.0f / VOX) - 0.5f;
        const float v  = (fmaf(t, dy, p1y) - XMIN) * (1.0f / VOX) - 0.5f;
        const int i0 = (int)rintf(u);
        const int j0 = (int)rintf(v);
        const bool tin = (t >= 0.0f) && (t <= 1.0f);
        float cfv = cf[lor];
        cfv = tin ? cfv : 0.0f;

        const float mi = (float)i0 - u;
        const float mj = (float)j0 - v;
        const float mim = mi - 1.0f, mip = mi + 1.0f;
        const float mjm = mj - 1.0f, mjp = mj + 1.0f;
        const float exm = __expf(-C2 * mim * mim) * cfv;   /* fold cfv */
        const float ex0 = __expf(-C2 * mi  * mi ) * cfv;
        const float exq = __expf(-C2 * mip * mip) * cfv;
        const float eym = __expf(-C2 * mjm * mjm);
        const float ey0 = __expf(-C2 * mj  * mj );
        const float eyq = __expf(-C2 * mjp * mjp);

        const int odd = j0 & 1;
        const float lA = odd ? eym : 0.0f;
        const float hA = odd ? ey0 : eym;
        const float lB = odd ? eyq : ey0;
        const float hB = odd ? 0.0f : eyq;
        const int p0 = min(max((j0 - 1) >> 1, 0), 62);
        const int ib = min(max(i0 - 1, 0), 125);

        const float exv[3] = {exm, ex0, exq};
#pragma unroll
        for (int a = 0; a < 3; ++a) {
            const float wa = exv[a] * FPSCALE;
            const int rowb = (ib + a) << 6;
            const unsigned long long vA =
                ((unsigned long long)(unsigned)(wa * hA) << 32) |
                 (unsigned long long)(unsigned)(wa * lA);
            const unsigned long long vB =
                ((unsigned long long)(unsigned)(wa * hB) << 32) |
                 (unsigned long long)(unsigned)(wa * lB);
            atomicAdd(&pl[rowb + p0], vA);
            atomicAdd(&pl[rowb + p0 + 1], vB);
        }
    }
    __syncthreads();

    float2* out2 = (float2*)(bpsub + ((size_t)sub * NG + k) * PLANE);
    for (int i = tid; i < NG * 64; i += 1024) {
        const unsigned long long vv = pl[i];
        out2[i] = make_float2((float)(unsigned)(vv & 0xffffffffULL) * INVFPSCALE,
                              (float)(unsigned)(vv >> 32) * INVFPSCALE);
    }
}

extern "C" void kernel_launch(void* const* d_in, const int* in_sizes, int n_in,
                              void* d_out, int out_size, void* d_ws, size_t ws_size,
                              hipStream_t stream) {
    const float* image = (const float*)d_in[0];
    const float* eff   = (const float*)d_in[1];
    const float* xl    = (const float*)d_in[2];
    const float* yl    = (const float*)d_in[3];
    const float* zl    = (const float*)d_in[4];
    float* out = (float*)d_out;

    char* ws = (char*)d_ws;
    float* imgP  = (float*)(ws);                       //  8 MB [k][ii][jj]
    float* bpsub = (float*)(ws + (size_t)( 8 << 20));  // 32 MB [sub][k][ii][jj]
    float* part8 = (float*)(ws + (size_t)(40 << 20));  //  4 MB [g][lor]
    float* cf    = (float*)(ws + (size_t)(44 << 20));  // 256 KB [lor]

    const dim3 tb(32, 8), tg(4, 4, 128);
    const dim3 pg(32, 16);   // proj: 32 LOR chunks x 16 plane groups

    // ---- z pass: (k,ii,jj) = (z,x,y)
    permute_k<1, 16384, 128, 0, 1, false, false><<<tg, tb, 0, stream>>>(image, imgP, nullptr, nullptr);
    plane_proj<<<pg, 1024, 0, stream>>>(zl, imgP, part8);
    reduce_cf<<<256, 256, 0, stream>>>(zl, part8, cf);
    plane_bp<<<128 * NSUB, 1024, 0, stream>>>(zl, cf, bpsub);
    // bp_z[z][x][y] -> out(x,y,z), first pass overwrites (no memset needed)
    permute_k<128, 1, 16384, 1, NSUB, false, false><<<tg, tb, 0, stream>>>(bpsub, out, nullptr, nullptr);

    // ---- x pass: (k,ii,jj) = (y,z,x)
    permute_k<128, 1, 16384, 1, 1, false, false><<<tg, tb, 0, stream>>>(image, imgP, nullptr, nullptr);
    plane_proj<<<pg, 1024, 0, stream>>>(xl, imgP, part8);
    reduce_cf<<<256, 256, 0, stream>>>(xl, part8, cf);
    plane_bp<<<128 * NSUB, 1024, 0, stream>>>(xl, cf, bpsub);
    permute_k<1, 16384, 128, 0, NSUB, true, false><<<tg, tb, 0, stream>>>(bpsub, out, nullptr, nullptr);

    // ---- y pass: (k,ii,jj) = (z,y,x); final permute fuses img/(eff+eps)*
    permute_k<1, 128, 16384, 0, 1, false, false><<<tg, tb, 0, stream>>>(image, imgP, nullptr, nullptr);
    plane_proj<<<pg, 1024, 0, stream>>>(yl, imgP, part8);
    reduce_cf<<<256, 256, 0, stream>>>(yl, part8, cf);
    plane_bp<<<128 * NSUB, 1024, 0, stream>>>(yl, cf, bpsub);
    permute_k<1, 128, 16384, 0, NSUB, true, true><<<tg, tb, 0, stream>>>(bpsub, out, image, eff);
}

// Round 12
// 276.020 us; speedup vs baseline: 5.5491x; 1.1247x over previous
//
#include <hip/hip_runtime.h>
#include <math.h>

#define NLOR  65536
#define NG    128
#define PLANE (NG * NG)
#define NSUB  4
#define KG    8               /* planes per proj block */
#define NKG   (NG / KG)       /* 16 plane groups */

#define VOX    1.671875f                 /* 214/128 exact */
#define XMIN  (-107.0f)
/* weight arg in cell units: (pi/2)(m+d)^2 */
#define C2     1.57079632679f

#define FPSCALE    8388608.0f            /* 2^23 fixed-point scale */
#define INVFPSCALE (1.0f / 8388608.0f)

// ---------------------------------------------------------------------------
// Generic tiled 3D permute; optional NSUM-subvolume sum, accumulate, and
// fused final epilogue out = img/(eff+1e-8)*(out + v).
// ---------------------------------------------------------------------------
template<int SP, int SQ, int SR, int CONTIG, int NSUM, bool ACCUM, bool FINAL>
__global__ __launch_bounds__(256)
void permute_k(const float* __restrict__ in, float* __restrict__ out,
               const float* __restrict__ img, const float* __restrict__ eff)
{
    __shared__ float tile[32][33];
    const int b  = blockIdx.z;
    const int c0 = blockIdx.x * 32;
    const int r0 = blockIdx.y * 32;
    const int tx = threadIdx.x, ty = threadIdx.y;

#pragma unroll
    for (int m = 0; m < 4; ++m) {
        const int C = c0 + tx;
        const int R = r0 + ty + 8 * m;
        const int P = (CONTIG == 0) ? C : b;
        const int Q = (CONTIG == 0) ? b : C;
        const int a = P * SP + Q * SQ + R * SR;
        float v = 0.0f;
#pragma unroll
        for (int s = 0; s < NSUM; ++s) v += in[a + s * NG * PLANE];
        tile[ty + 8 * m][tx] = v;
    }
    __syncthreads();
#pragma unroll
    for (int m = 0; m < 4; ++m) {
        const int R = r0 + tx;
        const int C = c0 + ty + 8 * m;
        const int P = (CONTIG == 0) ? C : b;
        const int Q = (CONTIG == 0) ? b : C;
        const int o = P * PLANE + Q * NG + R;
        float v = tile[tx][ty + 8 * m];
        if (ACCUM) v += out[o];
        if (FINAL) v = img[o] / (eff[o] + 1e-8f) * v;
        out[o] = v;
    }
}

// ---------------------------------------------------------------------------
// Merged z+y projection. z-planes serve both passes: z-LORs read the plane
// at (row=u, col=v); y-LORs are the same geometry with (u,v) swapped.
// Each thread carries 2 z-LOR + 2 y-LOR affine states across 8 planes.
// ---------------------------------------------------------------------------
__global__ __launch_bounds__(1024, 8)
void proj_zy(const float* __restrict__ zl, const float* __restrict__ yl,
             const float* __restrict__ imgPz,
             float* __restrict__ p8z, float* __restrict__ p8y)
{
    __shared__ float2 pl2[NG * 64];
    const int chunk = blockIdx.x;          // 32 chunks x 2048 LORs (per array)
    const int g     = blockIdx.y;          // 16 plane groups
    const int tid   = threadIdx.x;
    const int lor0  = chunk * 2048 + tid;

    float tA[4], uA[4], vA[4], dtA[4], duA[4], dvA[4], sA[4];
#pragma unroll
    for (int s = 0; s < 4; ++s) {
        const float* lors = (s < 2) ? zl : yl;
        const int lor = lor0 + (s & 1) * 1024;
        const float p1x = lors[0 * NLOR + lor];
        const float p1y = lors[1 * NLOR + lor];
        const float p1z = lors[2 * NLOR + lor];
        const float dx  = lors[3 * NLOR + lor] - p1x;
        const float dy  = lors[4 * NLOR + lor] - p1y;
        float dz = lors[5 * NLOR + lor] - p1z;
        dz = (fabsf(dz) < 1e-6f) ? 1e-6f : dz;
        const float rdz = 1.0f / dz;
        const float zc0 = XMIN + ((float)(g * KG) + 0.5f) * VOX;
        tA[s]  = (zc0 - p1z) * rdz;
        dtA[s] = VOX * rdz;
        float u = (fmaf(tA[s], dx, p1x) - XMIN) * (1.0f / VOX) - 0.5f;
        float v = (fmaf(tA[s], dy, p1y) - XMIN) * (1.0f / VOX) - 0.5f;
        float du = dx * rdz;
        float dv = dy * rdz;
        if (s >= 2) {                      /* y-LOR: swapped roles */
            float tmp = u; u = v; v = tmp;
            tmp = du; du = dv; dv = tmp;
        }
        uA[s] = u; vA[s] = v; duA[s] = du; dvA[s] = dv;
        sA[s] = 0.0f;
    }

    for (int st = 0; st < KG; ++st) {
        const int k = g * KG + st;
        const float4* src = (const float4*)(imgPz + k * PLANE);
        float4* dst = (float4*)pl2;
        for (int i = tid; i < PLANE / 4; i += 1024) dst[i] = src[i];
        __syncthreads();

        const float fst = (float)st;
#pragma unroll
        for (int s = 0; s < 4; ++s) {
            const float t = fmaf(fst, dtA[s], tA[s]);
            const float u = fmaf(fst, duA[s], uA[s]);
            const float v = fmaf(fst, dvA[s], vA[s]);
            const int i0 = (int)rintf(u);
            const int j0 = (int)rintf(v);
            const float mi = (float)i0 - u;
            const float mj = (float)j0 - v;
            const float mim = mi - 1.0f, mip = mi + 1.0f;
            const float mjm = mj - 1.0f, mjp = mj + 1.0f;
            const float exm = __expf(-C2 * mim * mim);
            const float ex0 = __expf(-C2 * mi  * mi );
            const float exq = __expf(-C2 * mip * mip);
            const float eym = __expf(-C2 * mjm * mjm);
            const float ey0 = __expf(-C2 * mj  * mj );
            const float eyq = __expf(-C2 * mjp * mjp);

            const int odd = j0 & 1;
            const float lA = odd ? eym : 0.0f;
            const float hA = odd ? ey0 : eym;
            const float lB = odd ? eyq : ey0;
            const float hB = odd ? 0.0f : eyq;
            const int p0 = min(max((j0 - 1) >> 1, 0), 62);
            const int ib = min(max(i0 - 1, 0), 125);

            const float exv[3] = {exm, ex0, exq};
            float acc = 0.0f;
#pragma unroll
            for (int a = 0; a < 3; ++a) {
                const int rowb = (ib + a) << 6;
                const float2 A = pl2[rowb + p0];
                const float2 B = pl2[rowb + p0 + 1];
                acc += exv[a] * (lA * A.x + hA * A.y + lB * B.x + hB * B.y);
            }
            const bool tin = (t >= 0.0f) && (t <= 1.0f);
            sA[s] += tin ? acc : 0.0f;
        }
        __syncthreads();
    }
    p8z[g * NLOR + lor0]        = sA[0];
    p8z[g * NLOR + lor0 + 1024] = sA[1];
    p8y[g * NLOR + lor0]        = sA[2];
    p8y[g * NLOR + lor0 + 1024] = sA[3];
}

// ---------------------------------------------------------------------------
// x-pass projection (unchanged structure).
// ---------------------------------------------------------------------------
__global__ __launch_bounds__(1024)
void plane_proj(const float* __restrict__ lors, const float* __restrict__ imgP,
                float* __restrict__ part8)
{
    __shared__ float2 pl2[NG * 64];
    const int chunk = blockIdx.x;
    const int g     = blockIdx.y;
    const int tid   = threadIdx.x;
    const int lor0  = chunk * 2048 + tid;

    float tA[2], uA[2], vA[2], dtA[2], duA[2], dvA[2], sA[2];
#pragma unroll
    for (int l = 0; l < 2; ++l) {
        const int lor = lor0 + l * 1024;
        const float p1x = lors[0 * NLOR + lor];
        const float p1y = lors[1 * NLOR + lor];
        const float p1z = lors[2 * NLOR + lor];
        const float dx  = lors[3 * NLOR + lor] - p1x;
        const float dy  = lors[4 * NLOR + lor] - p1y;
        float dz = lors[5 * NLOR + lor] - p1z;
        dz = (fabsf(dz) < 1e-6f) ? 1e-6f : dz;
        const float rdz = 1.0f / dz;
        const float zc0 = XMIN + ((float)(g * KG) + 0.5f) * VOX;
        tA[l]  = (zc0 - p1z) * rdz;
        dtA[l] = VOX * rdz;
        uA[l]  = (fmaf(tA[l], dx, p1x) - XMIN) * (1.0f / VOX) - 0.5f;
        vA[l]  = (fmaf(tA[l], dy, p1y) - XMIN) * (1.0f / VOX) - 0.5f;
        duA[l] = dx * rdz;
        dvA[l] = dy * rdz;
        sA[l]  = 0.0f;
    }

    for (int st = 0; st < KG; ++st) {
        const int k = g * KG + st;
        const float4* src = (const float4*)(imgP + k * PLANE);
        float4* dst = (float4*)pl2;
        for (int i = tid; i < PLANE / 4; i += 1024) dst[i] = src[i];
        __syncthreads();

        const float fst = (float)st;
#pragma unroll
        for (int l = 0; l < 2; ++l) {
            const float t = fmaf(fst, dtA[l], tA[l]);
            const float u = fmaf(fst, duA[l], uA[l]);
            const float v = fmaf(fst, dvA[l], vA[l]);
            const int i0 = (int)rintf(u);
            const int j0 = (int)rintf(v);
            const float mi = (float)i0 - u;
            const float mj = (float)j0 - v;
            const float mim = mi - 1.0f, mip = mi + 1.0f;
            const float mjm = mj - 1.0f, mjp = mj + 1.0f;
            const float exm = __expf(-C2 * mim * mim);
            const float ex0 = __expf(-C2 * mi  * mi );
            const float exq = __expf(-C2 * mip * mip);
            const float eym = __expf(-C2 * mjm * mjm);
            const float ey0 = __expf(-C2 * mj  * mj );
            const float eyq = __expf(-C2 * mjp * mjp);

            const int odd = j0 & 1;
            const float lA = odd ? eym : 0.0f;
            const float hA = odd ? ey0 : eym;
            const float lB = odd ? eyq : ey0;
            const float hB = odd ? 0.0f : eyq;
            const int p0 = min(max((j0 - 1) >> 1, 0), 62);
            const int ib = min(max(i0 - 1, 0), 125);

            const float exv[3] = {exm, ex0, exq};
            float acc = 0.0f;
#pragma unroll
            for (int a = 0; a < 3; ++a) {
                const int rowb = (ib + a) << 6;
                const float2 A = pl2[rowb + p0];
                const float2 B = pl2[rowb + p0 + 1];
                acc += exv[a] * (lA * A.x + hA * A.y + lB * B.x + hB * B.y);
            }
            const bool tin = (t >= 0.0f) && (t <= 1.0f);
            sA[l] += tin ? acc : 0.0f;
        }
        __syncthreads();
    }
    part8[g * NLOR + lor0]        = sA[0];
    part8[g * NLOR + lor0 + 1024] = sA[1];
}

// ---------------------------------------------------------------------------
// cf for all three passes in one dispatch (blockIdx.y selects the pass).
// ---------------------------------------------------------------------------
__global__ __launch_bounds__(256)
void reduce_cf3(const float* __restrict__ zl, const float* __restrict__ yl,
                const float* __restrict__ xl,
                const float* __restrict__ p8z, const float* __restrict__ p8y,
                const float* __restrict__ p8x,
                float* __restrict__ cfz, float* __restrict__ cfy,
                float* __restrict__ cfx)
{
    const int which = blockIdx.y;
    const float* lors  = (which == 0) ? zl  : (which == 1) ? yl  : xl;
    const float* part8 = (which == 0) ? p8z : (which == 1) ? p8y : p8x;
    float*       cf    = (which == 0) ? cfz : (which == 1) ? cfy : cfx;

    const int lor = blockIdx.x * 256 + threadIdx.x;
    float s = 0.0f;
#pragma unroll
    for (int g = 0; g < NKG; ++g) s += part8[g * NLOR + lor];

    const float p1x = lors[0 * NLOR + lor];
    const float p1y = lors[1 * NLOR + lor];
    const float p1z = lors[2 * NLOR + lor];
    const float dx  = lors[3 * NLOR + lor] - p1x;
    const float dy  = lors[4 * NLOR + lor] - p1y;
    const float dz0 = lors[5 * NLOR + lor] - p1z;
    const float L = sqrtf(dx * dx + dy * dy + dz0 * dz0);
    const float adz = fmaxf(fabsf(dz0), 1e-6f);
    const float dl = VOX * L / adz;
    cf[lor] = dl / (s * dl + 1e-8f);
}

// ---------------------------------------------------------------------------
// Shared deposit body for bp.
// ---------------------------------------------------------------------------
__device__ __forceinline__ void bp_deposit(const float* __restrict__ lors,
    const float* __restrict__ cf, int lor, float zc, bool swap,
    unsigned long long* __restrict__ pl)
{
    const float p1x = lors[0 * NLOR + lor];
    const float p1y = lors[1 * NLOR + lor];
    const float p1z = lors[2 * NLOR + lor];
    const float dx  = lors[3 * NLOR + lor] - p1x;
    const float dy  = lors[4 * NLOR + lor] - p1y;
    float dz = lors[5 * NLOR + lor] - p1z;
    dz = (fabsf(dz) < 1e-6f) ? 1e-6f : dz;
    const float t  = (zc - p1z) / dz;
    float u  = (fmaf(t, dx, p1x) - XMIN) * (1.0f / VOX) - 0.5f;
    float v  = (fmaf(t, dy, p1y) - XMIN) * (1.0f / VOX) - 0.5f;
    if (swap) { const float tmp = u; u = v; v = tmp; }
    const int i0 = (int)rintf(u);
    const int j0 = (int)rintf(v);
    const bool tin = (t >= 0.0f) && (t <= 1.0f);
    float cfv = cf[lor];
    cfv = tin ? cfv : 0.0f;

    const float mi = (float)i0 - u;
    const float mj = (float)j0 - v;
    const float mim = mi - 1.0f, mip = mi + 1.0f;
    const float mjm = mj - 1.0f, mjp = mj + 1.0f;
    const float exm = __expf(-C2 * mim * mim) * cfv;
    const float ex0 = __expf(-C2 * mi  * mi ) * cfv;
    const float exq = __expf(-C2 * mip * mip) * cfv;
    const float eym = __expf(-C2 * mjm * mjm);
    const float ey0 = __expf(-C2 * mj  * mj );
    const float eyq = __expf(-C2 * mjp * mjp);

    const int odd = j0 & 1;
    const float lA = odd ? eym : 0.0f;
    const float hA = odd ? ey0 : eym;
    const float lB = odd ? eyq : ey0;
    const float hB = odd ? 0.0f : eyq;
    const int p0 = min(max((j0 - 1) >> 1, 0), 62);
    const int ib = min(max(i0 - 1, 0), 125);

    const float exv[3] = {exm, ex0, exq};
#pragma unroll
    for (int a = 0; a < 3; ++a) {
        const float wa = exv[a] * FPSCALE;
        const int rowb = (ib + a) << 6;
        const unsigned long long vA =
            ((unsigned long long)(unsigned)(wa * hA) << 32) |
             (unsigned long long)(unsigned)(wa * lA);
        const unsigned long long vB =
            ((unsigned long long)(unsigned)(wa * hB) << 32) |
             (unsigned long long)(unsigned)(wa * lB);
        atomicAdd(&pl[rowb + p0], vA);
        atomicAdd(&pl[rowb + p0 + 1], vB);
    }
}

// ---------------------------------------------------------------------------
// Merged z+y backprojection into one shared [z][x][y] accumulator
// (y-LORs deposit with swapped roles).
// ---------------------------------------------------------------------------
__global__ __launch_bounds__(1024)
void bp_zy(const float* __restrict__ zl, const float* __restrict__ yl,
           const float* __restrict__ cfz, const float* __restrict__ cfy,
           float* __restrict__ bpsub)
{
    __shared__ unsigned long long pl[NG * 64];
    const int k   = blockIdx.x >> 2;
    const int sub = blockIdx.x & 3;
    const int tid = threadIdx.x;

    for (int i = tid; i < NG * 64; i += 1024) pl[i] = 0ULL;
    __syncthreads();

    const float zc = XMIN + ((float)k + 0.5f) * VOX;
    const int lo = sub * (NLOR / NSUB), hi = lo + NLOR / NSUB;
    for (int lor = lo + tid; lor < hi; lor += 1024)
        bp_deposit(zl, cfz, lor, zc, false, pl);
    for (int lor = lo + tid; lor < hi; lor += 1024)
        bp_deposit(yl, cfy, lor, zc, true, pl);
    __syncthreads();

    float2* out2 = (float2*)(bpsub + ((size_t)sub * NG + k) * PLANE);
    for (int i = tid; i < NG * 64; i += 1024) {
        const unsigned long long vv = pl[i];
        out2[i] = make_float2((float)(unsigned)(vv & 0xffffffffULL) * INVFPSCALE,
                              (float)(unsigned)(vv >> 32) * INVFPSCALE);
    }
}

// ---------------------------------------------------------------------------
// x-pass backprojection (unchanged structure).
// ---------------------------------------------------------------------------
__global__ __launch_bounds__(1024)
void plane_bp(const float* __restrict__ lors, const float* __restrict__ cf,
              float* __restrict__ bpsub)
{
    __shared__ unsigned long long pl[NG * 64];
    const int k   = blockIdx.x >> 2;
    const int sub = blockIdx.x & 3;
    const int tid = threadIdx.x;

    for (int i = tid; i < NG * 64; i += 1024) pl[i] = 0ULL;
    __syncthreads();

    const float zc = XMIN + ((float)k + 0.5f) * VOX;
    const int lo = sub * (NLOR / NSUB), hi = lo + NLOR / NSUB;
    for (int lor = lo + tid; lor < hi; lor += 1024)
        bp_deposit(lors, cf, lor, zc, false, pl);
    __syncthreads();

    float2* out2 = (float2*)(bpsub + ((size_t)sub * NG + k) * PLANE);
    for (int i = tid; i < NG * 64; i += 1024) {
        const unsigned long long vv = pl[i];
        out2[i] = make_float2((float)(unsigned)(vv & 0xffffffffULL) * INVFPSCALE,
                              (float)(unsigned)(vv >> 32) * INVFPSCALE);
    }
}

extern "C" void kernel_launch(void* const* d_in, const int* in_sizes, int n_in,
                              void* d_out, int out_size, void* d_ws, size_t ws_size,
                              hipStream_t stream) {
    const float* image = (const float*)d_in[0];
    const float* eff   = (const float*)d_in[1];
    const float* xl    = (const float*)d_in[2];
    const float* yl    = (const float*)d_in[3];
    const float* zl    = (const float*)d_in[4];
    float* out = (float*)d_out;

    char* ws = (char*)d_ws;
    float* imgPz = (float*)(ws);                        //  8 MB [z][x][y]
    float* imgPx = (float*)(ws + (size_t)( 8 << 20));   //  8 MB [y][z][x]
    float* bpsub = (float*)(ws + (size_t)(16 << 20));   // 32 MB [sub][k][ii][jj]
    float* p8z   = (float*)(ws + (size_t)(48 << 20));   //  4 MB
    float* p8y   = (float*)(ws + (size_t)(52 << 20));   //  4 MB
    float* p8x   = (float*)(ws + (size_t)(56 << 20));   //  4 MB
    float* cfz   = (float*)(ws + (size_t)(60 << 20));                 // 256 KB
    float* cfy   = (float*)(ws + (size_t)(60 << 20) + (256 << 10));   // 256 KB
    float* cfx   = (float*)(ws + (size_t)(60 << 20) + (512 << 10));   // 256 KB

    const dim3 tb(32, 8), tg(4, 4, 128);
    const dim3 pg(32, 16);

    // image permutes: z/y share [z][x][y]; x uses [y][z][x]
    permute_k<1, 16384, 128, 0, 1, false, false><<<tg, tb, 0, stream>>>(image, imgPz, nullptr, nullptr);
    permute_k<128, 1, 16384, 1, 1, false, false><<<tg, tb, 0, stream>>>(image, imgPx, nullptr, nullptr);

    // projections
    proj_zy<<<pg, 1024, 0, stream>>>(zl, yl, imgPz, p8z, p8y);
    plane_proj<<<pg, 1024, 0, stream>>>(xl, imgPx, p8x);

    // correction factors, all passes
    reduce_cf3<<<dim3(256, 3), 256, 0, stream>>>(zl, yl, xl, p8z, p8y, p8x, cfz, cfy, cfx);

    // z+y backprojection into shared accumulator; overwrite out via permute
    bp_zy<<<128 * NSUB, 1024, 0, stream>>>(zl, yl, cfz, cfy, bpsub);
    permute_k<128, 1, 16384, 1, NSUB, false, false><<<tg, tb, 0, stream>>>(bpsub, out, nullptr, nullptr);

    // x backprojection (reuses bpsub); accumulate + fused finalize
    plane_bp<<<128 * NSUB, 1024, 0, stream>>>(xl, cfx, bpsub);
    permute_k<1, 16384, 128, 0, NSUB, true, true><<<tg, tb, 0, stream>>>(bpsub, out, image, eff);
}

// Round 13
// 255.558 us; speedup vs baseline: 5.9934x; 1.0801x over previous
//
#include <hip/hip_runtime.h>
#include <math.h>

#define NLOR  65536
#define NG    128
#define PLANE (NG * NG)
#define NSUB  4
#define KG    8               /* planes per proj block */
#define NKG   (NG / KG)       /* 16 plane groups */

#define VOX    1.671875f                 /* 214/128 exact */
#define XMIN  (-107.0f)
/* weight arg in cell units: (pi/2)(m+d)^2 */
#define C2     1.57079632679f

#define FPSCALE    8388608.0f            /* 2^23 fixed-point scale */
#define INVFPSCALE (1.0f / 8388608.0f)

// ---------------------------------------------------------------------------
// Tiled 3D permute body. Output layout ((P*128 + Q)*128 + R); input addr
// P*SP + Q*SQ + R*SR (+ s*volume for NSUM sub-buffers). CONTIG: which of
// {P(0),Q(1)} is the input-contiguous (tiled) axis; the other is b.
// ---------------------------------------------------------------------------
template<int SP, int SQ, int SR, int CONTIG, int NSUM, bool ACCUM, bool FINAL>
__device__ __forceinline__ void permute_body(
    const float* __restrict__ in, float* __restrict__ out,
    const float* __restrict__ img, const float* __restrict__ eff,
    int b, float (*tile)[33])
{
    const int c0 = blockIdx.x * 32;
    const int r0 = blockIdx.y * 32;
    const int tx = threadIdx.x, ty = threadIdx.y;

#pragma unroll
    for (int m = 0; m < 4; ++m) {
        const int C = c0 + tx;
        const int R = r0 + ty + 8 * m;
        const int P = (CONTIG == 0) ? C : b;
        const int Q = (CONTIG == 0) ? b : C;
        const int a = P * SP + Q * SQ + R * SR;
        float v = 0.0f;
#pragma unroll
        for (int s = 0; s < NSUM; ++s) v += in[a + s * NG * PLANE];
        tile[ty + 8 * m][tx] = v;
    }
    __syncthreads();
#pragma unroll
    for (int m = 0; m < 4; ++m) {
        const int R = r0 + tx;
        const int C = c0 + ty + 8 * m;
        const int P = (CONTIG == 0) ? C : b;
        const int Q = (CONTIG == 0) ? b : C;
        const int o = P * PLANE + Q * NG + R;
        float v = tile[tx][ty + 8 * m];
        if (ACCUM) v += out[o];
        if (FINAL) v = img[o] / (eff[o] + 1e-8f) * v;
        out[o] = v;
    }
}

// Both image permutes in one launch: b<128 -> imgPz [z][x][y]; else imgPx [y][z][x].
__global__ __launch_bounds__(256)
void perm_img2(const float* __restrict__ image,
               float* __restrict__ imgPz, float* __restrict__ imgPx)
{
    __shared__ float tile[32][33];
    const int b = blockIdx.z;
    if (b < 128)
        permute_body<1, 16384, 128, 0, 1, false, false>(image, imgPz, nullptr, nullptr, b, tile);
    else
        permute_body<128, 1, 16384, 1, 1, false, false>(image, imgPx, nullptr, nullptr, b - 128, tile);
}

__global__ __launch_bounds__(256)
void perm_outA(const float* __restrict__ in, float* __restrict__ out)
{
    __shared__ float tile[32][33];
    permute_body<128, 1, 16384, 1, NSUB, false, false>(in, out, nullptr, nullptr, blockIdx.z, tile);
}

__global__ __launch_bounds__(256)
void perm_outB(const float* __restrict__ in, float* __restrict__ out,
               const float* __restrict__ img, const float* __restrict__ eff)
{
    __shared__ float tile[32][33];
    permute_body<1, 16384, 128, 0, NSUB, true, true>(in, out, img, eff, blockIdx.z, tile);
}

// ---------------------------------------------------------------------------
// Projection: per-(LOR, plane-group) partial sums. NS LOR streams (z+y share
// the z-plane family, the y stream with u/v swapped; x family has 1 stream).
// ---------------------------------------------------------------------------
template<int NS>
__device__ __forceinline__ void proj_body(
    const float* const* lorsv, const float* __restrict__ imgP,
    float* const* p8v, float2* pl2)
{
    const int chunk = blockIdx.x;
    const int g     = blockIdx.y;
    const int tid   = threadIdx.x;
    const int lor0  = chunk * 2048 + tid;

    float tA[2 * NS], uA[2 * NS], vA[2 * NS], dtA[2 * NS], duA[2 * NS], dvA[2 * NS], sA[2 * NS];
#pragma unroll
    for (int s = 0; s < 2 * NS; ++s) {
        const float* lors = lorsv[s >> 1];
        const bool swap = (NS == 2) && (s >= 2);
        const int lor = lor0 + (s & 1) * 1024;
        const float p1x = lors[0 * NLOR + lor];
        const float p1y = lors[1 * NLOR + lor];
        const float p1z = lors[2 * NLOR + lor];
        const float dx  = lors[3 * NLOR + lor] - p1x;
        const float dy  = lors[4 * NLOR + lor] - p1y;
        float dz = lors[5 * NLOR + lor] - p1z;
        dz = (fabsf(dz) < 1e-6f) ? 1e-6f : dz;
        const float rdz = 1.0f / dz;
        const float zc0 = XMIN + ((float)(g * KG) + 0.5f) * VOX;
        tA[s]  = (zc0 - p1z) * rdz;
        dtA[s] = VOX * rdz;
        float u = (fmaf(tA[s], dx, p1x) - XMIN) * (1.0f / VOX) - 0.5f;
        float v = (fmaf(tA[s], dy, p1y) - XMIN) * (1.0f / VOX) - 0.5f;
        float du = dx * rdz;
        float dv = dy * rdz;
        if (swap) {
            float tmp = u; u = v; v = tmp;
            tmp = du; du = dv; dv = tmp;
        }
        uA[s] = u; vA[s] = v; duA[s] = du; dvA[s] = dv;
        sA[s] = 0.0f;
    }

    for (int st = 0; st < KG; ++st) {
        const int k = g * KG + st;
        const float4* src = (const float4*)(imgP + k * PLANE);
        float4* dst = (float4*)pl2;
        for (int i = tid; i < PLANE / 4; i += 1024) dst[i] = src[i];
        __syncthreads();

        const float fst = (float)st;
#pragma unroll
        for (int s = 0; s < 2 * NS; ++s) {
            const float t = fmaf(fst, dtA[s], tA[s]);
            const float u = fmaf(fst, duA[s], uA[s]);
            const float v = fmaf(fst, dvA[s], vA[s]);
            const int i0 = (int)rintf(u);
            const int j0 = (int)rintf(v);
            const float mi = (float)i0 - u;
            const float mj = (float)j0 - v;
            const float mim = mi - 1.0f, mip = mi + 1.0f;
            const float mjm = mj - 1.0f, mjp = mj + 1.0f;
            const float exm = __expf(-C2 * mim * mim);
            const float ex0 = __expf(-C2 * mi  * mi );
            const float exq = __expf(-C2 * mip * mip);
            const float eym = __expf(-C2 * mjm * mjm);
            const float ey0 = __expf(-C2 * mj  * mj );
            const float eyq = __expf(-C2 * mjp * mjp);

            const int odd = j0 & 1;
            const float lA = odd ? eym : 0.0f;
            const float hA = odd ? ey0 : eym;
            const float lB = odd ? eyq : ey0;
            const float hB = odd ? 0.0f : eyq;
            const int p0 = min(max((j0 - 1) >> 1, 0), 62);
            const int ib = min(max(i0 - 1, 0), 125);

            const float exv[3] = {exm, ex0, exq};
            float acc = 0.0f;
#pragma unroll
            for (int a = 0; a < 3; ++a) {
                const int rowb = (ib + a) << 6;
                const float2 A = pl2[rowb + p0];
                const float2 B = pl2[rowb + p0 + 1];
                acc += exv[a] * (lA * A.x + hA * A.y + lB * B.x + hB * B.y);
            }
            const bool tin = (t >= 0.0f) && (t <= 1.0f);
            sA[s] += tin ? acc : 0.0f;
        }
        __syncthreads();
    }
#pragma unroll
    for (int s = 0; s < NS; ++s) {
        p8v[s][g * NLOR + lor0]        = sA[2 * s];
        p8v[s][g * NLOR + lor0 + 1024] = sA[2 * s + 1];
    }
}

// blockIdx.z==0: z+y streams on imgPz; ==1: x stream on imgPx.
__global__ __launch_bounds__(1024, 8)
void proj_all(const float* __restrict__ zl, const float* __restrict__ yl,
              const float* __restrict__ xl,
              const float* __restrict__ imgPz, const float* __restrict__ imgPx,
              float* __restrict__ p8z, float* __restrict__ p8y,
              float* __restrict__ p8x)
{
    __shared__ float2 pl2[NG * 64];
    if (blockIdx.z == 0) {
        const float* lorsv[2] = {zl, yl};
        float* p8v[2] = {p8z, p8y};
        proj_body<2>(lorsv, imgPz, p8v, pl2);
    } else {
        const float* lorsv[1] = {xl};
        float* p8v[1] = {p8x};
        proj_body<1>(lorsv, imgPx, p8v, pl2);
    }
}

// ---------------------------------------------------------------------------
// cf for all three passes in one dispatch (blockIdx.y selects the pass).
// ---------------------------------------------------------------------------
__global__ __launch_bounds__(256)
void reduce_cf3(const float* __restrict__ zl, const float* __restrict__ yl,
                const float* __restrict__ xl,
                const float* __restrict__ p8z, const float* __restrict__ p8y,
                const float* __restrict__ p8x,
                float* __restrict__ cfz, float* __restrict__ cfy,
                float* __restrict__ cfx)
{
    const int which = blockIdx.y;
    const float* lors  = (which == 0) ? zl  : (which == 1) ? yl  : xl;
    const float* part8 = (which == 0) ? p8z : (which == 1) ? p8y : p8x;
    float*       cf    = (which == 0) ? cfz : (which == 1) ? cfy : cfx;

    const int lor = blockIdx.x * 256 + threadIdx.x;
    float s = 0.0f;
#pragma unroll
    for (int g = 0; g < NKG; ++g) s += part8[g * NLOR + lor];

    const float p1x = lors[0 * NLOR + lor];
    const float p1y = lors[1 * NLOR + lor];
    const float p1z = lors[2 * NLOR + lor];
    const float dx  = lors[3 * NLOR + lor] - p1x;
    const float dy  = lors[4 * NLOR + lor] - p1y;
    const float dz0 = lors[5 * NLOR + lor] - p1z;
    const float L = sqrtf(dx * dx + dy * dy + dz0 * dz0);
    const float adz = fmaxf(fabsf(dz0), 1e-6f);
    const float dl = VOX * L / adz;
    cf[lor] = dl / (s * dl + 1e-8f);
}

// ---------------------------------------------------------------------------
// bp deposit: 6 packed fixed-point ds_add_u64 per LOR*plane. FPSCALE folded
// into the cf factor.
// ---------------------------------------------------------------------------
__device__ __forceinline__ void bp_deposit(const float* __restrict__ lors,
    const float* __restrict__ cf, int lor, float zc, bool swap,
    unsigned long long* __restrict__ pl)
{
    const float p1x = lors[0 * NLOR + lor];
    const float p1y = lors[1 * NLOR + lor];
    const float p1z = lors[2 * NLOR + lor];
    const float dx  = lors[3 * NLOR + lor] - p1x;
    const float dy  = lors[4 * NLOR + lor] - p1y;
    float dz = lors[5 * NLOR + lor] - p1z;
    dz = (fabsf(dz) < 1e-6f) ? 1e-6f : dz;
    const float t  = (zc - p1z) / dz;
    float u  = (fmaf(t, dx, p1x) - XMIN) * (1.0f / VOX) - 0.5f;
    float v  = (fmaf(t, dy, p1y) - XMIN) * (1.0f / VOX) - 0.5f;
    if (swap) { const float tmp = u; u = v; v = tmp; }
    const int i0 = (int)rintf(u);
    const int j0 = (int)rintf(v);
    const bool tin = (t >= 0.0f) && (t <= 1.0f);
    float cfs = cf[lor] * FPSCALE;
    cfs = tin ? cfs : 0.0f;

    const float mi = (float)i0 - u;
    const float mj = (float)j0 - v;
    const float mim = mi - 1.0f, mip = mi + 1.0f;
    const float mjm = mj - 1.0f, mjp = mj + 1.0f;
    const float exm = __expf(-C2 * mim * mim) * cfs;
    const float ex0 = __expf(-C2 * mi  * mi ) * cfs;
    const float exq = __expf(-C2 * mip * mip) * cfs;
    const float eym = __expf(-C2 * mjm * mjm);
    const float ey0 = __expf(-C2 * mj  * mj );
    const float eyq = __expf(-C2 * mjp * mjp);

    const int odd = j0 & 1;
    const float lA = odd ? eym : 0.0f;
    const float hA = odd ? ey0 : eym;
    const float lB = odd ? eyq : ey0;
    const float hB = odd ? 0.0f : eyq;
    const int p0 = min(max((j0 - 1) >> 1, 0), 62);
    const int ib = min(max(i0 - 1, 0), 125);

    const float exv[3] = {exm, ex0, exq};
#pragma unroll
    for (int a = 0; a < 3; ++a) {
        const float wa = exv[a];
        const int rowb = (ib + a) << 6;
        const unsigned long long vA =
            ((unsigned long long)(unsigned)(wa * hA) << 32) |
             (unsigned long long)(unsigned)(wa * lA);
        const unsigned long long vB =
            ((unsigned long long)(unsigned)(wa * hB) << 32) |
             (unsigned long long)(unsigned)(wa * lB);
        atomicAdd(&pl[rowb + p0], vA);
        atomicAdd(&pl[rowb + p0 + 1], vB);
    }
}

// ---------------------------------------------------------------------------
// All backprojection in one launch. blockIdx.y==0: z+y -> bpsubA (z-family);
// ==1: x -> bpsubB (y-family).
// ---------------------------------------------------------------------------
__global__ __launch_bounds__(1024)
void bp_all(const float* __restrict__ zl, const float* __restrict__ yl,
            const float* __restrict__ xl,
            const float* __restrict__ cfz, const float* __restrict__ cfy,
            const float* __restrict__ cfx,
            float* __restrict__ bpsubA, float* __restrict__ bpsubB)
{
    __shared__ unsigned long long pl[NG * 64];
    const int k   = blockIdx.x >> 2;
    const int sub = blockIdx.x & 3;
    const int tid = threadIdx.x;

    for (int i = tid; i < NG * 64; i += 1024) pl[i] = 0ULL;
    __syncthreads();

    const float zc = XMIN + ((float)k + 0.5f) * VOX;
    const int lo = sub * (NLOR / NSUB), hi = lo + NLOR / NSUB;
    float* bpsub;
    if (blockIdx.y == 0) {
        for (int lor = lo + tid; lor < hi; lor += 1024)
            bp_deposit(zl, cfz, lor, zc, false, pl);
        for (int lor = lo + tid; lor < hi; lor += 1024)
            bp_deposit(yl, cfy, lor, zc, true, pl);
        bpsub = bpsubA;
    } else {
        for (int lor = lo + tid; lor < hi; lor += 1024)
            bp_deposit(xl, cfx, lor, zc, false, pl);
        bpsub = bpsubB;
    }
    __syncthreads();

    float2* out2 = (float2*)(bpsub + ((size_t)sub * NG + k) * PLANE);
    for (int i = tid; i < NG * 64; i += 1024) {
        const unsigned long long vv = pl[i];
        out2[i] = make_float2((float)(unsigned)(vv & 0xffffffffULL) * INVFPSCALE,
                              (float)(unsigned)(vv >> 32) * INVFPSCALE);
    }
}

extern "C" void kernel_launch(void* const* d_in, const int* in_sizes, int n_in,
                              void* d_out, int out_size, void* d_ws, size_t ws_size,
                              hipStream_t stream) {
    const float* image = (const float*)d_in[0];
    const float* eff   = (const float*)d_in[1];
    const float* xl    = (const float*)d_in[2];
    const float* yl    = (const float*)d_in[3];
    const float* zl    = (const float*)d_in[4];
    float* out = (float*)d_out;

    char* ws = (char*)d_ws;
    float* imgPz  = (float*)(ws);                        //  8 MB [z][x][y]
    float* imgPx  = (float*)(ws + (size_t)( 8 << 20));   //  8 MB [y][z][x]
    float* bpsubA = (float*)(ws + (size_t)(16 << 20));   // 32 MB [sub][z][x][y]
    float* bpsubB = (float*)(ws + (size_t)(48 << 20));   // 32 MB [sub][y][z][x]
    float* p8z    = (float*)(ws + (size_t)(80 << 20));   //  4 MB
    float* p8y    = (float*)(ws + (size_t)(84 << 20));   //  4 MB
    float* p8x    = (float*)(ws + (size_t)(88 << 20));   //  4 MB
    float* cfz    = (float*)(ws + (size_t)(92 << 20));                 // 256 KB
    float* cfy    = (float*)(ws + (size_t)(92 << 20) + (256 << 10));   // 256 KB
    float* cfx    = (float*)(ws + (size_t)(92 << 20) + (512 << 10));   // 256 KB

    const dim3 tb(32, 8);

    // 1) both image permutes
    perm_img2<<<dim3(4, 4, 256), tb, 0, stream>>>(image, imgPz, imgPx);
    // 2) all projections (z+y family | x family)
    proj_all<<<dim3(32, 16, 2), 1024, 0, stream>>>(zl, yl, xl, imgPz, imgPx, p8z, p8y, p8x);
    // 3) correction factors, all passes
    reduce_cf3<<<dim3(256, 3), 256, 0, stream>>>(zl, yl, xl, p8z, p8y, p8x, cfz, cfy, cfx);
    // 4) all backprojection (z+y -> bpsubA | x -> bpsubB)
    bp_all<<<dim3(128 * NSUB, 2), 1024, 0, stream>>>(zl, yl, xl, cfz, cfy, cfx, bpsubA, bpsubB);
    // 5) z+y accumulator -> out (overwrite)
    perm_outA<<<dim3(4, 4, 128), tb, 0, stream>>>(bpsubA, out);
    // 6) x accumulator -> out (accumulate + fused finalize)
    perm_outB<<<dim3(4, 4, 128), tb, 0, stream>>>(bpsubB, out, image, eff);
}

// Round 14
// 238.322 us; speedup vs baseline: 6.4268x; 1.0723x over previous
//
#include <hip/hip_runtime.h>
#include <hip/hip_fp16.h>
#include <math.h>

#define NLOR  65536
#define NG    128
#define PLANE (NG * NG)
#define NSUB  4
#define KG    8               /* planes per proj block */
#define NKG   (NG / KG)       /* 16 plane groups */

#define VOX    1.671875f                 /* 214/128 exact */
#define XMIN  (-107.0f)
/* weight arg in cell units: (pi/2)(m+d)^2 */
#define C2     1.57079632679f

#define FPSCALE    8388608.0f            /* 2^23 fixed-point scale */
#define INVFPSCALE (1.0f / 8388608.0f)

// ---------------------------------------------------------------------------
// Tiled 3D permute body (f32 out). Output ((P*128 + Q)*128 + R); input addr
// P*SP + Q*SQ + R*SR (+ s*volume for NSUM sub-buffers). CONTIG: which of
// {P(0),Q(1)} is the tiled (input-contiguous) axis; the other is b.
// ---------------------------------------------------------------------------
template<int SP, int SQ, int SR, int CONTIG, int NSUM, bool ACCUM, bool FINAL>
__device__ __forceinline__ void permute_body(
    const float* __restrict__ in, float* __restrict__ out,
    const float* __restrict__ img, const float* __restrict__ eff,
    int b, float (*tile)[33])
{
    const int c0 = blockIdx.x * 32;
    const int r0 = blockIdx.y * 32;
    const int tx = threadIdx.x, ty = threadIdx.y;

#pragma unroll
    for (int m = 0; m < 4; ++m) {
        const int C = c0 + tx;
        const int R = r0 + ty + 8 * m;
        const int P = (CONTIG == 0) ? C : b;
        const int Q = (CONTIG == 0) ? b : C;
        const int a = P * SP + Q * SQ + R * SR;
        float v = 0.0f;
#pragma unroll
        for (int s = 0; s < NSUM; ++s) v += in[a + s * NG * PLANE];
        tile[ty + 8 * m][tx] = v;
    }
    __syncthreads();
#pragma unroll
    for (int m = 0; m < 4; ++m) {
        const int R = r0 + tx;
        const int C = c0 + ty + 8 * m;
        const int P = (CONTIG == 0) ? C : b;
        const int Q = (CONTIG == 0) ? b : C;
        const int o = P * PLANE + Q * NG + R;
        float v = tile[tx][ty + 8 * m];
        if (ACCUM) v += out[o];
        if (FINAL) v = img[o] / (eff[o] + 1e-8f) * v;
        out[o] = v;
    }
}

// Same body but writing __half (for the staged image volumes).
template<int SP, int SQ, int SR, int CONTIG>
__device__ __forceinline__ void permute_half_body(
    const float* __restrict__ in, __half* __restrict__ out,
    int b, float (*tile)[33])
{
    const int c0 = blockIdx.x * 32;
    const int r0 = blockIdx.y * 32;
    const int tx = threadIdx.x, ty = threadIdx.y;

#pragma unroll
    for (int m = 0; m < 4; ++m) {
        const int C = c0 + tx;
        const int R = r0 + ty + 8 * m;
        const int P = (CONTIG == 0) ? C : b;
        const int Q = (CONTIG == 0) ? b : C;
        tile[ty + 8 * m][tx] = in[P * SP + Q * SQ + R * SR];
    }
    __syncthreads();
#pragma unroll
    for (int m = 0; m < 4; ++m) {
        const int R = r0 + tx;
        const int C = c0 + ty + 8 * m;
        const int P = (CONTIG == 0) ? C : b;
        const int Q = (CONTIG == 0) ? b : C;
        const int o = P * PLANE + Q * NG + R;
        out[o] = __float2half(tile[tx][ty + 8 * m]);
    }
}

// Both image permutes in one launch: b<128 -> imgPz [z][x][y]; else imgPx [y][z][x].
__global__ __launch_bounds__(256)
void perm_img2(const float* __restrict__ image,
               __half* __restrict__ imgPz, __half* __restrict__ imgPx)
{
    __shared__ float tile[32][33];
    const int b = blockIdx.z;
    if (b < 128)
        permute_half_body<1, 16384, 128, 0>(image, imgPz, b, tile);
    else
        permute_half_body<128, 1, 16384, 1>(image, imgPx, b - 128, tile);
}

__global__ __launch_bounds__(256)
void perm_outA(const float* __restrict__ in, float* __restrict__ out)
{
    __shared__ float tile[32][33];
    permute_body<128, 1, 16384, 1, NSUB, false, false>(in, out, nullptr, nullptr, blockIdx.z, tile);
}

__global__ __launch_bounds__(256)
void perm_outB(const float* __restrict__ in, float* __restrict__ out,
               const float* __restrict__ img, const float* __restrict__ eff)
{
    __shared__ float tile[32][33];
    permute_body<1, 16384, 128, 0, NSUB, true, true>(in, out, img, eff, blockIdx.z, tile);
}

// ---------------------------------------------------------------------------
// Projection. Plane staged in LDS as half2 pairs (32 KB): 2x ds_read_b32 per
// row over 32 banks (vs b64 over 16 bank-pairs) -> ~half the conflicts, and
// half the staging bytes. Math stays f32. NS LOR streams (z+y share the
// z-plane family, y with u/v swapped; x family has 1 stream).
// ---------------------------------------------------------------------------
template<int NS>
__device__ __forceinline__ void proj_body(
    const float* const* lorsv, const unsigned int* __restrict__ imgP,
    float* const* p8v, unsigned int* pl)
{
    const int chunk = blockIdx.x;
    const int g     = blockIdx.y;
    const int tid   = threadIdx.x;
    const int lor0  = chunk * 2048 + tid;

    float tA[2 * NS], uA[2 * NS], vA[2 * NS], dtA[2 * NS], duA[2 * NS], dvA[2 * NS], sA[2 * NS];
#pragma unroll
    for (int s = 0; s < 2 * NS; ++s) {
        const float* lors = lorsv[s >> 1];
        const bool swap = (NS == 2) && (s >= 2);
        const int lor = lor0 + (s & 1) * 1024;
        const float p1x = lors[0 * NLOR + lor];
        const float p1y = lors[1 * NLOR + lor];
        const float p1z = lors[2 * NLOR + lor];
        const float dx  = lors[3 * NLOR + lor] - p1x;
        const float dy  = lors[4 * NLOR + lor] - p1y;
        float dz = lors[5 * NLOR + lor] - p1z;
        dz = (fabsf(dz) < 1e-6f) ? 1e-6f : dz;
        const float rdz = 1.0f / dz;
        const float zc0 = XMIN + ((float)(g * KG) + 0.5f) * VOX;
        tA[s]  = (zc0 - p1z) * rdz;
        dtA[s] = VOX * rdz;
        float u = (fmaf(tA[s], dx, p1x) - XMIN) * (1.0f / VOX) - 0.5f;
        float v = (fmaf(tA[s], dy, p1y) - XMIN) * (1.0f / VOX) - 0.5f;
        float du = dx * rdz;
        float dv = dy * rdz;
        if (swap) {
            float tmp = u; u = v; v = tmp;
            tmp = du; du = dv; dv = tmp;
        }
        uA[s] = u; vA[s] = v; duA[s] = du; dvA[s] = dv;
        sA[s] = 0.0f;
    }

    for (int st = 0; st < KG; ++st) {
        const int k = g * KG + st;
        const uint4* src = (const uint4*)(imgP + k * (NG * 64));
        uint4* dst = (uint4*)pl;
        for (int i = tid; i < (NG * 64) / 4; i += 1024) dst[i] = src[i];
        __syncthreads();

        const float fst = (float)st;
#pragma unroll
        for (int s = 0; s < 2 * NS; ++s) {
            const float t = fmaf(fst, dtA[s], tA[s]);
            const float u = fmaf(fst, duA[s], uA[s]);
            const float v = fmaf(fst, dvA[s], vA[s]);
            const int i0 = (int)rintf(u);
            const int j0 = (int)rintf(v);
            const float mi = (float)i0 - u;
            const float mj = (float)j0 - v;
            const float mim = mi - 1.0f, mip = mi + 1.0f;
            const float mjm = mj - 1.0f, mjp = mj + 1.0f;
            const float exm = __expf(-C2 * mim * mim);
            const float ex0 = __expf(-C2 * mi  * mi );
            const float exq = __expf(-C2 * mip * mip);
            const float eym = __expf(-C2 * mjm * mjm);
            const float ey0 = __expf(-C2 * mj  * mj );
            const float eyq = __expf(-C2 * mjp * mjp);

            const int odd = j0 & 1;
            const float lA = odd ? eym : 0.0f;
            const float hA = odd ? ey0 : eym;
            const float lB = odd ? eyq : ey0;
            const float hB = odd ? 0.0f : eyq;
            const int p0 = min(max((j0 - 1) >> 1, 0), 62);
            const int ib = min(max(i0 - 1, 0), 125);

            const float exv[3] = {exm, ex0, exq};
            float acc = 0.0f;
#pragma unroll
            for (int a = 0; a < 3; ++a) {
                const int rowb = (ib + a) << 6;
                const unsigned int Aw = pl[rowb + p0];
                const unsigned int Bw = pl[rowb + p0 + 1];
                const float2 A = __half22float2(*reinterpret_cast<const __half2*>(&Aw));
                const float2 B = __half22float2(*reinterpret_cast<const __half2*>(&Bw));
                acc += exv[a] * (lA * A.x + hA * A.y + lB * B.x + hB * B.y);
            }
            const bool tin = (t >= 0.0f) && (t <= 1.0f);
            sA[s] += tin ? acc : 0.0f;
        }
        __syncthreads();
    }
#pragma unroll
    for (int s = 0; s < NS; ++s) {
        p8v[s][g * NLOR + lor0]        = sA[2 * s];
        p8v[s][g * NLOR + lor0 + 1024] = sA[2 * s + 1];
    }
}

// blockIdx.z==0: z+y streams on imgPz; ==1: x stream on imgPx.
__global__ __launch_bounds__(1024, 8)
void proj_all(const float* __restrict__ zl, const float* __restrict__ yl,
              const float* __restrict__ xl,
              const unsigned int* __restrict__ imgPz, const unsigned int* __restrict__ imgPx,
              float* __restrict__ p8z, float* __restrict__ p8y,
              float* __restrict__ p8x)
{
    __shared__ unsigned int pl[NG * 64];     /* 32 KB: plane as half2 pairs */
    if (blockIdx.z == 0) {
        const float* lorsv[2] = {zl, yl};
        float* p8v[2] = {p8z, p8y};
        proj_body<2>(lorsv, imgPz, p8v, pl);
    } else {
        const float* lorsv[1] = {xl};
        float* p8v[1] = {p8x};
        proj_body<1>(lorsv, imgPx, p8v, pl);
    }
}

// ---------------------------------------------------------------------------
// cf for all three passes in one dispatch (blockIdx.y selects the pass).
// ---------------------------------------------------------------------------
__global__ __launch_bounds__(256)
void reduce_cf3(const float* __restrict__ zl, const float* __restrict__ yl,
                const float* __restrict__ xl,
                const float* __restrict__ p8z, const float* __restrict__ p8y,
                const float* __restrict__ p8x,
                float* __restrict__ cfz, float* __restrict__ cfy,
                float* __restrict__ cfx)
{
    const int which = blockIdx.y;
    const float* lors  = (which == 0) ? zl  : (which == 1) ? yl  : xl;
    const float* part8 = (which == 0) ? p8z : (which == 1) ? p8y : p8x;
    float*       cf    = (which == 0) ? cfz : (which == 1) ? cfy : cfx;

    const int lor = blockIdx.x * 256 + threadIdx.x;
    float s = 0.0f;
#pragma unroll
    for (int g = 0; g < NKG; ++g) s += part8[g * NLOR + lor];

    const float p1x = lors[0 * NLOR + lor];
    const float p1y = lors[1 * NLOR + lor];
    const float p1z = lors[2 * NLOR + lor];
    const float dx  = lors[3 * NLOR + lor] - p1x;
    const float dy  = lors[4 * NLOR + lor] - p1y;
    const float dz0 = lors[5 * NLOR + lor] - p1z;
    const float L = sqrtf(dx * dx + dy * dy + dz0 * dz0);
    const float adz = fmaxf(fabsf(dz0), 1e-6f);
    const float dl = VOX * L / adz;
    cf[lor] = dl / (s * dl + 1e-8f);
}

// ---------------------------------------------------------------------------
// bp deposit: 6 packed fixed-point ds_add_u64 per LOR*plane (f32 exact math).
// ---------------------------------------------------------------------------
__device__ __forceinline__ void bp_deposit(const float* __restrict__ lors,
    const float* __restrict__ cf, int lor, float zc, bool swap,
    unsigned long long* __restrict__ pl)
{
    const float p1x = lors[0 * NLOR + lor];
    const float p1y = lors[1 * NLOR + lor];
    const float p1z = lors[2 * NLOR + lor];
    const float dx  = lors[3 * NLOR + lor] - p1x;
    const float dy  = lors[4 * NLOR + lor] - p1y;
    float dz = lors[5 * NLOR + lor] - p1z;
    dz = (fabsf(dz) < 1e-6f) ? 1e-6f : dz;
    const float t  = (zc - p1z) / dz;
    float u  = (fmaf(t, dx, p1x) - XMIN) * (1.0f / VOX) - 0.5f;
    float v  = (fmaf(t, dy, p1y) - XMIN) * (1.0f / VOX) - 0.5f;
    if (swap) { const float tmp = u; u = v; v = tmp; }
    const int i0 = (int)rintf(u);
    const int j0 = (int)rintf(v);
    const bool tin = (t >= 0.0f) && (t <= 1.0f);
    float cfs = cf[lor] * FPSCALE;
    cfs = tin ? cfs : 0.0f;

    const float mi = (float)i0 - u;
    const float mj = (float)j0 - v;
    const float mim = mi - 1.0f, mip = mi + 1.0f;
    const float mjm = mj - 1.0f, mjp = mj + 1.0f;
    const float exm = __expf(-C2 * mim * mim) * cfs;
    const float ex0 = __expf(-C2 * mi  * mi ) * cfs;
    const float exq = __expf(-C2 * mip * mip) * cfs;
    const float eym = __expf(-C2 * mjm * mjm);
    const float ey0 = __expf(-C2 * mj  * mj );
    const float eyq = __expf(-C2 * mjp * mjp);

    const int odd = j0 & 1;
    const float lA = odd ? eym : 0.0f;
    const float hA = odd ? ey0 : eym;
    const float lB = odd ? eyq : ey0;
    const float hB = odd ? 0.0f : eyq;
    const int p0 = min(max((j0 - 1) >> 1, 0), 62);
    const int ib = min(max(i0 - 1, 0), 125);

    const float exv[3] = {exm, ex0, exq};
#pragma unroll
    for (int a = 0; a < 3; ++a) {
        const float wa = exv[a];
        const int rowb = (ib + a) << 6;
        const unsigned long long vA =
            ((unsigned long long)(unsigned)(wa * hA) << 32) |
             (unsigned long long)(unsigned)(wa * lA);
        const unsigned long long vB =
            ((unsigned long long)(unsigned)(wa * hB) << 32) |
             (unsigned long long)(unsigned)(wa * lB);
        atomicAdd(&pl[rowb + p0], vA);
        atomicAdd(&pl[rowb + p0 + 1], vB);
    }
}

// ---------------------------------------------------------------------------
// All backprojection in one launch. blockIdx.y==0: z+y -> bpsubA (z-family);
// ==1: x -> bpsubB (y-family).
// ---------------------------------------------------------------------------
__global__ __launch_bounds__(1024)
void bp_all(const float* __restrict__ zl, const float* __restrict__ yl,
            const float* __restrict__ xl,
            const float* __restrict__ cfz, const float* __restrict__ cfy,
            const float* __restrict__ cfx,
            float* __restrict__ bpsubA, float* __restrict__ bpsubB)
{
    __shared__ unsigned long long pl[NG * 64];
    const int k   = blockIdx.x >> 2;
    const int sub = blockIdx.x & 3;
    const int tid = threadIdx.x;

    for (int i = tid; i < NG * 64; i += 1024) pl[i] = 0ULL;
    __syncthreads();

    const float zc = XMIN + ((float)k + 0.5f) * VOX;
    const int lo = sub * (NLOR / NSUB), hi = lo + NLOR / NSUB;
    float* bpsub;
    if (blockIdx.y == 0) {
        for (int lor = lo + tid; lor < hi; lor += 1024)
            bp_deposit(zl, cfz, lor, zc, false, pl);
        for (int lor = lo + tid; lor < hi; lor += 1024)
            bp_deposit(yl, cfy, lor, zc, true, pl);
        bpsub = bpsubA;
    } else {
        for (int lor = lo + tid; lor < hi; lor += 1024)
            bp_deposit(xl, cfx, lor, zc, false, pl);
        bpsub = bpsubB;
    }
    __syncthreads();

    float2* out2 = (float2*)(bpsub + ((size_t)sub * NG + k) * PLANE);
    for (int i = tid; i < NG * 64; i += 1024) {
        const unsigned long long vv = pl[i];
        out2[i] = make_float2((float)(unsigned)(vv & 0xffffffffULL) * INVFPSCALE,
                              (float)(unsigned)(vv >> 32) * INVFPSCALE);
    }
}

extern "C" void kernel_launch(void* const* d_in, const int* in_sizes, int n_in,
                              void* d_out, int out_size, void* d_ws, size_t ws_size,
                              hipStream_t stream) {
    const float* image = (const float*)d_in[0];
    const float* eff   = (const float*)d_in[1];
    const float* xl    = (const float*)d_in[2];
    const float* yl    = (const float*)d_in[3];
    const float* zl    = (const float*)d_in[4];
    float* out = (float*)d_out;

    char* ws = (char*)d_ws;
    __half* imgPz = (__half*)(ws);                       //  4 MB [z][x][y] half
    __half* imgPx = (__half*)(ws + (size_t)( 4 << 20));  //  4 MB [y][z][x] half
    float* bpsubA = (float*)(ws + (size_t)( 8 << 20));   // 32 MB [sub][z][x][y]
    float* bpsubB = (float*)(ws + (size_t)(40 << 20));   // 32 MB [sub][y][z][x]
    float* p8z    = (float*)(ws + (size_t)(72 << 20));   //  4 MB
    float* p8y    = (float*)(ws + (size_t)(76 << 20));   //  4 MB
    float* p8x    = (float*)(ws + (size_t)(80 << 20));   //  4 MB
    float* cfz    = (float*)(ws + (size_t)(84 << 20));                 // 256 KB
    float* cfy    = (float*)(ws + (size_t)(84 << 20) + (256 << 10));   // 256 KB
    float* cfx    = (float*)(ws + (size_t)(84 << 20) + (512 << 10));   // 256 KB

    const dim3 tb(32, 8);

    // 1) both image permutes (f32 -> half volumes)
    perm_img2<<<dim3(4, 4, 256), tb, 0, stream>>>(image, imgPz, imgPx);
    // 2) all projections (z+y family | x family)
    proj_all<<<dim3(32, 16, 2), 1024, 0, stream>>>(zl, yl, xl,
        (const unsigned int*)imgPz, (const unsigned int*)imgPx, p8z, p8y, p8x);
    // 3) correction factors, all passes
    reduce_cf3<<<dim3(256, 3), 256, 0, stream>>>(zl, yl, xl, p8z, p8y, p8x, cfz, cfy, cfx);
    // 4) all backprojection (z+y -> bpsubA | x -> bpsubB)
    bp_all<<<dim3(128 * NSUB, 2), 1024, 0, stream>>>(zl, yl, xl, cfz, cfy, cfx, bpsubA, bpsubB);
    // 5) z+y accumulator -> out (overwrite)
    perm_outA<<<dim3(4, 4, 128), tb, 0, stream>>>(bpsubA, out);
    // 6) x accumulator -> out (accumulate + fused finalize)
    perm_outB<<<dim3(4, 4, 128), tb, 0, stream>>>(bpsubB, out, image, eff);
}

// Round 15
// 233.155 us; speedup vs baseline: 6.5693x; 1.0222x over previous
//
#include <hip/hip_runtime.h>
#include <hip/hip_fp16.h>
#include <math.h>

#define NLOR  65536
#define NG    128
#define PLANE (NG * NG)
#define NSUB  2
#define KG    8               /* planes per proj block */
#define NKG   (NG / KG)       /* 16 plane groups */

#define VOX    1.671875f                 /* 214/128 exact */
#define XMIN  (-107.0f)
/* weight arg in cell units: (pi/2)(m+d)^2 */
#define C2     1.57079632679f

#define FPSCALE    8388608.0f            /* 2^23 fixed-point scale */
#define INVFPSCALE (1.0f / 8388608.0f)

// ---------------------------------------------------------------------------
// Tiled 3D permute body (f32 out). Output ((P*128 + Q)*128 + R); input addr
// P*SP + Q*SQ + R*SR (+ s*volume for NSUM sub-buffers). CONTIG: which of
// {P(0),Q(1)} is the tiled (input-contiguous) axis; the other is b.
// ---------------------------------------------------------------------------
template<int SP, int SQ, int SR, int CONTIG, int NSUM, bool ACCUM, bool FINAL>
__device__ __forceinline__ void permute_body(
    const float* __restrict__ in, float* __restrict__ out,
    const float* __restrict__ img, const float* __restrict__ eff,
    int b, float (*tile)[33])
{
    const int c0 = blockIdx.x * 32;
    const int r0 = blockIdx.y * 32;
    const int tx = threadIdx.x, ty = threadIdx.y;

#pragma unroll
    for (int m = 0; m < 4; ++m) {
        const int C = c0 + tx;
        const int R = r0 + ty + 8 * m;
        const int P = (CONTIG == 0) ? C : b;
        const int Q = (CONTIG == 0) ? b : C;
        const int a = P * SP + Q * SQ + R * SR;
        float v = 0.0f;
#pragma unroll
        for (int s = 0; s < NSUM; ++s) v += in[a + s * NG * PLANE];
        tile[ty + 8 * m][tx] = v;
    }
    __syncthreads();
#pragma unroll
    for (int m = 0; m < 4; ++m) {
        const int R = r0 + tx;
        const int C = c0 + ty + 8 * m;
        const int P = (CONTIG == 0) ? C : b;
        const int Q = (CONTIG == 0) ? b : C;
        const int o = P * PLANE + Q * NG + R;
        float v = tile[tx][ty + 8 * m];
        if (ACCUM) v += out[o];
        if (FINAL) v = img[o] / (eff[o] + 1e-8f) * v;
        out[o] = v;
    }
}

// Same body but writing __half (for the staged image volumes).
template<int SP, int SQ, int SR, int CONTIG>
__device__ __forceinline__ void permute_half_body(
    const float* __restrict__ in, __half* __restrict__ out,
    int b, float (*tile)[33])
{
    const int c0 = blockIdx.x * 32;
    const int r0 = blockIdx.y * 32;
    const int tx = threadIdx.x, ty = threadIdx.y;

#pragma unroll
    for (int m = 0; m < 4; ++m) {
        const int C = c0 + tx;
        const int R = r0 + ty + 8 * m;
        const int P = (CONTIG == 0) ? C : b;
        const int Q = (CONTIG == 0) ? b : C;
        tile[ty + 8 * m][tx] = in[P * SP + Q * SQ + R * SR];
    }
    __syncthreads();
#pragma unroll
    for (int m = 0; m < 4; ++m) {
        const int R = r0 + tx;
        const int C = c0 + ty + 8 * m;
        const int P = (CONTIG == 0) ? C : b;
        const int Q = (CONTIG == 0) ? b : C;
        const int o = P * PLANE + Q * NG + R;
        out[o] = __float2half(tile[tx][ty + 8 * m]);
    }
}

// Both image permutes in one launch: b<128 -> imgPz [z][x][y]; else imgPx [y][z][x].
__global__ __launch_bounds__(256)
void perm_img2(const float* __restrict__ image,
               __half* __restrict__ imgPz, __half* __restrict__ imgPx)
{
    __shared__ float tile[32][33];
    const int b = blockIdx.z;
    if (b < 128)
        permute_half_body<1, 16384, 128, 0>(image, imgPz, b, tile);
    else
        permute_half_body<128, 1, 16384, 1>(image, imgPx, b - 128, tile);
}

__global__ __launch_bounds__(256)
void perm_outA(const float* __restrict__ in, float* __restrict__ out)
{
    __shared__ float tile[32][33];
    permute_body<128, 1, 16384, 1, NSUB, false, false>(in, out, nullptr, nullptr, blockIdx.z, tile);
}

__global__ __launch_bounds__(256)
void perm_outB(const float* __restrict__ in, float* __restrict__ out,
               const float* __restrict__ img, const float* __restrict__ eff)
{
    __shared__ float tile[32][33];
    permute_body<1, 16384, 128, 0, NSUB, true, true>(in, out, img, eff, blockIdx.z, tile);
}

// ---------------------------------------------------------------------------
// Projection. Plane staged in LDS as half2 pairs (32 KB). blockIdx.x = plane
// group (XCD = linear_id % 8 = g % 8 -> all chunks of one group share an XCD
// L2, so each XCD fetches only its own groups' planes). blockIdx.y = chunk.
// ---------------------------------------------------------------------------
template<int NS>
__device__ __forceinline__ void proj_body(
    const float* const* lorsv, const unsigned int* __restrict__ imgP,
    float* const* p8v, unsigned int* pl)
{
    const int g     = blockIdx.x;          // 16 plane groups (XCD selector)
    const int chunk = blockIdx.y;          // 32 chunks x 2048 LORs
    const int tid   = threadIdx.x;
    const int lor0  = chunk * 2048 + tid;

    float tA[2 * NS], uA[2 * NS], vA[2 * NS], dtA[2 * NS], duA[2 * NS], dvA[2 * NS], sA[2 * NS];
#pragma unroll
    for (int s = 0; s < 2 * NS; ++s) {
        const float* lors = lorsv[s >> 1];
        const bool swap = (NS == 2) && (s >= 2);
        const int lor = lor0 + (s & 1) * 1024;
        const float p1x = lors[0 * NLOR + lor];
        const float p1y = lors[1 * NLOR + lor];
        const float p1z = lors[2 * NLOR + lor];
        const float dx  = lors[3 * NLOR + lor] - p1x;
        const float dy  = lors[4 * NLOR + lor] - p1y;
        float dz = lors[5 * NLOR + lor] - p1z;
        dz = (fabsf(dz) < 1e-6f) ? 1e-6f : dz;
        const float rdz = 1.0f / dz;
        const float zc0 = XMIN + ((float)(g * KG) + 0.5f) * VOX;
        tA[s]  = (zc0 - p1z) * rdz;
        dtA[s] = VOX * rdz;
        float u = (fmaf(tA[s], dx, p1x) - XMIN) * (1.0f / VOX) - 0.5f;
        float v = (fmaf(tA[s], dy, p1y) - XMIN) * (1.0f / VOX) - 0.5f;
        float du = dx * rdz;
        float dv = dy * rdz;
        if (swap) {
            float tmp = u; u = v; v = tmp;
            tmp = du; du = dv; dv = tmp;
        }
        uA[s] = u; vA[s] = v; duA[s] = du; dvA[s] = dv;
        sA[s] = 0.0f;
    }

    for (int st = 0; st < KG; ++st) {
        const int k = g * KG + st;
        const uint4* src = (const uint4*)(imgP + k * (NG * 64));
        uint4* dst = (uint4*)pl;
        for (int i = tid; i < (NG * 64) / 4; i += 1024) dst[i] = src[i];
        __syncthreads();

        const float fst = (float)st;
#pragma unroll
        for (int s = 0; s < 2 * NS; ++s) {
            const float t = fmaf(fst, dtA[s], tA[s]);
            const float u = fmaf(fst, duA[s], uA[s]);
            const float v = fmaf(fst, dvA[s], vA[s]);
            const int i0 = (int)rintf(u);
            const int j0 = (int)rintf(v);
            const float mi = (float)i0 - u;
            const float mj = (float)j0 - v;
            const float mim = mi - 1.0f, mip = mi + 1.0f;
            const float mjm = mj - 1.0f, mjp = mj + 1.0f;
            const float exm = __expf(-C2 * mim * mim);
            const float ex0 = __expf(-C2 * mi  * mi );
            const float exq = __expf(-C2 * mip * mip);
            const float eym = __expf(-C2 * mjm * mjm);
            const float ey0 = __expf(-C2 * mj  * mj );
            const float eyq = __expf(-C2 * mjp * mjp);

            const int odd = j0 & 1;
            const float lA = odd ? eym : 0.0f;
            const float hA = odd ? ey0 : eym;
            const float lB = odd ? eyq : ey0;
            const float hB = odd ? 0.0f : eyq;
            const int p0 = min(max((j0 - 1) >> 1, 0), 62);
            const int ib = min(max(i0 - 1, 0), 125);

            const float exv[3] = {exm, ex0, exq};
            float acc = 0.0f;
#pragma unroll
            for (int a = 0; a < 3; ++a) {
                const int rowb = (ib + a) << 6;
                const unsigned int Aw = pl[rowb + p0];
                const unsigned int Bw = pl[rowb + p0 + 1];
                const float2 A = __half22float2(*reinterpret_cast<const __half2*>(&Aw));
                const float2 B = __half22float2(*reinterpret_cast<const __half2*>(&Bw));
                acc += exv[a] * (lA * A.x + hA * A.y + lB * B.x + hB * B.y);
            }
            const bool tin = (t >= 0.0f) && (t <= 1.0f);
            sA[s] += tin ? acc : 0.0f;
        }
        __syncthreads();
    }
#pragma unroll
    for (int s = 0; s < NS; ++s) {
        p8v[s][g * NLOR + lor0]        = sA[2 * s];
        p8v[s][g * NLOR + lor0 + 1024] = sA[2 * s + 1];
    }
}

// blockIdx.z==0: z+y streams on imgPz; ==1: x stream on imgPx.
__global__ __launch_bounds__(1024, 8)
void proj_all(const float* __restrict__ zl, const float* __restrict__ yl,
              const float* __restrict__ xl,
              const unsigned int* __restrict__ imgPz, const unsigned int* __restrict__ imgPx,
              float* __restrict__ p8z, float* __restrict__ p8y,
              float* __restrict__ p8x)
{
    __shared__ unsigned int pl[NG * 64];     /* 32 KB: plane as half2 pairs */
    if (blockIdx.z == 0) {
        const float* lorsv[2] = {zl, yl};
        float* p8v[2] = {p8z, p8y};
        proj_body<2>(lorsv, imgPz, p8v, pl);
    } else {
        const float* lorsv[1] = {xl};
        float* p8v[1] = {p8x};
        proj_body<1>(lorsv, imgPx, p8v, pl);
    }
}

// ---------------------------------------------------------------------------
// cf for all three passes in one dispatch (blockIdx.y selects the pass).
// ---------------------------------------------------------------------------
__global__ __launch_bounds__(256)
void reduce_cf3(const float* __restrict__ zl, const float* __restrict__ yl,
                const float* __restrict__ xl,
                const float* __restrict__ p8z, const float* __restrict__ p8y,
                const float* __restrict__ p8x,
                float* __restrict__ cfz, float* __restrict__ cfy,
                float* __restrict__ cfx)
{
    const int which = blockIdx.y;
    const float* lors  = (which == 0) ? zl  : (which == 1) ? yl  : xl;
    const float* part8 = (which == 0) ? p8z : (which == 1) ? p8y : p8x;
    float*       cf    = (which == 0) ? cfz : (which == 1) ? cfy : cfx;

    const int lor = blockIdx.x * 256 + threadIdx.x;
    float s = 0.0f;
#pragma unroll
    for (int g = 0; g < NKG; ++g) s += part8[g * NLOR + lor];

    const float p1x = lors[0 * NLOR + lor];
    const float p1y = lors[1 * NLOR + lor];
    const float p1z = lors[2 * NLOR + lor];
    const float dx  = lors[3 * NLOR + lor] - p1x;
    const float dy  = lors[4 * NLOR + lor] - p1y;
    const float dz0 = lors[5 * NLOR + lor] - p1z;
    const float L = sqrtf(dx * dx + dy * dy + dz0 * dz0);
    const float adz = fmaxf(fabsf(dz0), 1e-6f);
    const float dl = VOX * L / adz;
    cf[lor] = dl / (s * dl + 1e-8f);
}

// ---------------------------------------------------------------------------
// bp deposit: 6 packed fixed-point ds_add_u64 per LOR*plane (f32 exact math).
// ---------------------------------------------------------------------------
__device__ __forceinline__ void bp_deposit(const float* __restrict__ lors,
    const float* __restrict__ cf, int lor, float zc, bool swap,
    unsigned long long* __restrict__ pl)
{
    const float p1x = lors[0 * NLOR + lor];
    const float p1y = lors[1 * NLOR + lor];
    const float p1z = lors[2 * NLOR + lor];
    const float dx  = lors[3 * NLOR + lor] - p1x;
    const float dy  = lors[4 * NLOR + lor] - p1y;
    float dz = lors[5 * NLOR + lor] - p1z;
    dz = (fabsf(dz) < 1e-6f) ? 1e-6f : dz;
    const float t  = (zc - p1z) / dz;
    float u  = (fmaf(t, dx, p1x) - XMIN) * (1.0f / VOX) - 0.5f;
    float v  = (fmaf(t, dy, p1y) - XMIN) * (1.0f / VOX) - 0.5f;
    if (swap) { const float tmp = u; u = v; v = tmp; }
    const int i0 = (int)rintf(u);
    const int j0 = (int)rintf(v);
    const bool tin = (t >= 0.0f) && (t <= 1.0f);
    float cfs = cf[lor] * FPSCALE;
    cfs = tin ? cfs : 0.0f;

    const float mi = (float)i0 - u;
    const float mj = (float)j0 - v;
    const float mim = mi - 1.0f, mip = mi + 1.0f;
    const float mjm = mj - 1.0f, mjp = mj + 1.0f;
    const float exm = __expf(-C2 * mim * mim) * cfs;
    const float ex0 = __expf(-C2 * mi  * mi ) * cfs;
    const float exq = __expf(-C2 * mip * mip) * cfs;
    const float eym = __expf(-C2 * mjm * mjm);
    const float ey0 = __expf(-C2 * mj  * mj );
    const float eyq = __expf(-C2 * mjp * mjp);

    const int odd = j0 & 1;
    const float lA = odd ? eym : 0.0f;
    const float hA = odd ? ey0 : eym;
    const float lB = odd ? eyq : ey0;
    const float hB = odd ? 0.0f : eyq;
    const int p0 = min(max((j0 - 1) >> 1, 0), 62);
    const int ib = min(max(i0 - 1, 0), 125);

    const float exv[3] = {exm, ex0, exq};
#pragma unroll
    for (int a = 0; a < 3; ++a) {
        const float wa = exv[a];
        const int rowb = (ib + a) << 6;
        const unsigned long long vA =
            ((unsigned long long)(unsigned)(wa * hA) << 32) |
             (unsigned long long)(unsigned)(wa * lA);
        const unsigned long long vB =
            ((unsigned long long)(unsigned)(wa * hB) << 32) |
             (unsigned long long)(unsigned)(wa * lB);
        atomicAdd(&pl[rowb + p0], vA);
        atomicAdd(&pl[rowb + p0 + 1], vB);
    }
}

// ---------------------------------------------------------------------------
// All backprojection in one launch. blockIdx.y==0: z+y -> bpsubA (z-family);
// ==1: x -> bpsubB (y-family). NSUB=2 sub-volumes.
// ---------------------------------------------------------------------------
__global__ __launch_bounds__(1024)
void bp_all(const float* __restrict__ zl, const float* __restrict__ yl,
            const float* __restrict__ xl,
            const float* __restrict__ cfz, const float* __restrict__ cfy,
            const float* __restrict__ cfx,
            float* __restrict__ bpsubA, float* __restrict__ bpsubB)
{
    __shared__ unsigned long long pl[NG * 64];
    const int k   = blockIdx.x >> 1;
    const int sub = blockIdx.x & 1;
    const int tid = threadIdx.x;

    for (int i = tid; i < NG * 64; i += 1024) pl[i] = 0ULL;
    __syncthreads();

    const float zc = XMIN + ((float)k + 0.5f) * VOX;
    const int lo = sub * (NLOR / NSUB), hi = lo + NLOR / NSUB;
    float* bpsub;
    if (blockIdx.y == 0) {
        for (int lor = lo + tid; lor < hi; lor += 1024)
            bp_deposit(zl, cfz, lor, zc, false, pl);
        for (int lor = lo + tid; lor < hi; lor += 1024)
            bp_deposit(yl, cfy, lor, zc, true, pl);
        bpsub = bpsubA;
    } else {
        for (int lor = lo + tid; lor < hi; lor += 1024)
            bp_deposit(xl, cfx, lor, zc, false, pl);
        bpsub = bpsubB;
    }
    __syncthreads();

    float2* out2 = (float2*)(bpsub + ((size_t)sub * NG + k) * PLANE);
    for (int i = tid; i < NG * 64; i += 1024) {
        const unsigned long long vv = pl[i];
        out2[i] = make_float2((float)(unsigned)(vv & 0xffffffffULL) * INVFPSCALE,
                              (float)(unsigned)(vv >> 32) * INVFPSCALE);
    }
}

extern "C" void kernel_launch(void* const* d_in, const int* in_sizes, int n_in,
                              void* d_out, int out_size, void* d_ws, size_t ws_size,
                              hipStream_t stream) {
    const float* image = (const float*)d_in[0];
    const float* eff   = (const float*)d_in[1];
    const float* xl    = (const float*)d_in[2];
    const float* yl    = (const float*)d_in[3];
    const float* zl    = (const float*)d_in[4];
    float* out = (float*)d_out;

    char* ws = (char*)d_ws;
    __half* imgPz = (__half*)(ws);                       //  4 MB [z][x][y] half
    __half* imgPx = (__half*)(ws + (size_t)( 4 << 20));  //  4 MB [y][z][x] half
    float* bpsubA = (float*)(ws + (size_t)( 8 << 20));   // 16 MB [sub][z][x][y]
    float* bpsubB = (float*)(ws + (size_t)(24 << 20));   // 16 MB [sub][y][z][x]
    float* p8z    = (float*)(ws + (size_t)(40 << 20));   //  4 MB
    float* p8y    = (float*)(ws + (size_t)(44 << 20));   //  4 MB
    float* p8x    = (float*)(ws + (size_t)(48 << 20));   //  4 MB
    float* cfz    = (float*)(ws + (size_t)(52 << 20));                 // 256 KB
    float* cfy    = (float*)(ws + (size_t)(52 << 20) + (256 << 10));   // 256 KB
    float* cfx    = (float*)(ws + (size_t)(52 << 20) + (512 << 10));   // 256 KB

    const dim3 tb(32, 8);

    // 1) both image permutes (f32 -> half volumes)
    perm_img2<<<dim3(4, 4, 256), tb, 0, stream>>>(image, imgPz, imgPx);
    // 2) all projections; grid.x = plane group for XCD L2 locality
    proj_all<<<dim3(16, 32, 2), 1024, 0, stream>>>(zl, yl, xl,
        (const unsigned int*)imgPz, (const unsigned int*)imgPx, p8z, p8y, p8x);
    // 3) correction factors, all passes
    reduce_cf3<<<dim3(256, 3), 256, 0, stream>>>(zl, yl, xl, p8z, p8y, p8x, cfz, cfy, cfx);
    // 4) all backprojection (z+y -> bpsubA | x -> bpsubB)
    bp_all<<<dim3(128 * NSUB, 2), 1024, 0, stream>>>(zl, yl, xl, cfz, cfy, cfx, bpsubA, bpsubB);
    // 5) z+y accumulator -> out (overwrite)
    perm_outA<<<dim3(4, 4, 128), tb, 0, stream>>>(bpsubA, out);
    // 6) x accumulator -> out (accumulate + fused finalize)
    perm_outB<<<dim3(4, 4, 128), tb, 0, stream>>>(bpsubB, out, image, eff);
}